// Round 9
// baseline (1388.752 us; speedup 1.0000x reference)
//
#include <hip/hip_runtime.h>
#include <hip/hip_fp16.h>

// Problem constants (fixed by the reference)
constexpr int N = 50000;
constexpr int E = 800000;
constexpr int G = 512;
constexpr int H = 128;
constexpr long long NH = (long long)N * H;   // 6,400,000 elements
constexpr float EPS = 1e-5f;
constexpr int NB_SCAN = 196;                 // ceil(50000/256)

typedef _Float16 f16x8 __attribute__((ext_vector_type(8)));
typedef _Float16 f16x2 __attribute__((ext_vector_type(2)));
typedef float f32x4 __attribute__((ext_vector_type(4)));

// ---------------------------------------------------------------------------
// vn[g][c] = vn_emb[c]
__global__ void k_init_vn(const float* __restrict__ vn_emb, float* __restrict__ vn) {
  int idx = blockIdx.x * 256 + threadIdx.x;   // G*H = 65536 exactly
  vn[idx] = vn_emb[idx & 127];
}

// fp32 -> fp16 bulk convert (float4 -> half2 x2), grid covers n4 exactly
__global__ void k_tof16(const float* __restrict__ in, __half* __restrict__ out, int n4) {
  int i = blockIdx.x * 256 + threadIdx.x;
  if (i >= n4) return;
  float4 v = reinterpret_cast<const float4*>(in)[i];
  __half2* o = reinterpret_cast<__half2*>(out);
  o[i * 2]     = __floats2half2_rn(v.x, v.y);
  o[i * 2 + 1] = __floats2half2_rn(v.z, v.w);
}

// Wt[c][k] = (half) W[(row0+k)*ldw + c], K=128 fixed; one layer per blockIdx.y
__global__ void k_wt(const float* __restrict__ W, __half* __restrict__ Wt,
                     int ldw, int row0, int cols, long long wstride, int wtstride) {
  const float* Wl = W + (long long)blockIdx.y * wstride;
  __half* Wtl = Wt + (long long)blockIdx.y * wtstride;
  int idx = blockIdx.x * 256 + threadIdx.x;   // cols*128, exact multiple of 256
  int k = idx & 127, c = idx >> 7;
  Wtl[c * 128 + k] = __float2half(Wl[(long long)(row0 + k) * ldw + c]);
}

// h16[r][:] += vn[batch[r]][:]  (half2 lanes, grid = N*64/256 = 12500 exact)
__global__ void k_addvn16(__half* __restrict__ h16, const float* __restrict__ vn,
                          const int* __restrict__ batch) {
  int i2 = blockIdx.x * 256 + threadIdx.x;
  int r = i2 >> 6;
  int b = batch[r];
  __half2 hv = reinterpret_cast<__half2*>(h16)[i2];
  float2 vv = reinterpret_cast<const float2*>(vn)[(b << 6) + (i2 & 63)];
  reinterpret_cast<__half2*>(h16)[i2] =
      __floats2half2_rn(__low2float(hv) + vv.x, __high2float(hv) + vv.y);
}

// gstart[g] = lower_bound(batch, g); gstart[G] = N  (batch is sorted)
__global__ void k_gstart(const int* __restrict__ batch, int* __restrict__ gstart) {
  int g = threadIdx.x;   // one block of 512
  int lo = 0, hi = N;
  while (lo < hi) { int mid = (lo + hi) >> 1; if (batch[mid] < g) lo = mid + 1; else hi = mid; }
  gstart[g] = lo;
  if (g == 0) gstart[G] = N;
}

// ---------------------------------------------------------------------------
// CSR build: histogram -> 2-level exclusive scan -> idx-scatter -> gather-permute.
// idx-scatter randomly writes ONLY the 4B edge id; permute then reads edge_attr
// as full 64B lines (no partial-line RMW) and streams eap/srcp out coalesced.
__global__ void k_hist(const int* __restrict__ dst, int* __restrict__ cnt) {
  int e = blockIdx.x * 256 + threadIdx.x;   // grid covers E exactly
  atomicAdd(&cnt[dst[e]], 1);
}

__global__ void k_scan_block(const int* __restrict__ cnt, int* __restrict__ off,
                             int* __restrict__ bsum) {
  __shared__ int s[256];
  int idx = blockIdx.x * 256 + threadIdx.x;
  int v = (idx < N) ? cnt[idx] : 0;
  s[threadIdx.x] = v;
  __syncthreads();
  for (int o = 1; o < 256; o <<= 1) {
    int t = (threadIdx.x >= o) ? s[threadIdx.x - o] : 0;
    __syncthreads();
    s[threadIdx.x] += t;
    __syncthreads();
  }
  if (idx < N) off[idx + 1] = s[threadIdx.x];
  if (threadIdx.x == 255) bsum[blockIdx.x] = s[255];
  if (idx == 0) off[0] = 0;
}

__global__ void k_scan_bsum(int* __restrict__ bsum) {   // single block
  __shared__ int s[256];
  int v = (threadIdx.x < NB_SCAN) ? bsum[threadIdx.x] : 0;
  s[threadIdx.x] = v;
  __syncthreads();
  for (int o = 1; o < 256; o <<= 1) {
    int t = (threadIdx.x >= o) ? s[threadIdx.x - o] : 0;
    __syncthreads();
    s[threadIdx.x] += t;
    __syncthreads();
  }
  if (threadIdx.x < NB_SCAN) bsum[threadIdx.x] = s[threadIdx.x];  // inclusive
}

__global__ void k_scan_add(int* __restrict__ off, const int* __restrict__ bsum) {
  int idx = blockIdx.x * 256 + threadIdx.x;
  if (idx < N && blockIdx.x > 0) off[idx + 1] += bsum[blockIdx.x - 1];
}

__global__ void k_scatter_idx(const int* __restrict__ dst, const int* __restrict__ off,
                              int* __restrict__ cur, int* __restrict__ eidp) {
  int e = blockIdx.x * 256 + threadIdx.x;   // grid covers E exactly
  int d = dst[e];
  int p = off[d] + atomicAdd(&cur[d], 1);
  eidp[p] = e;
}

__global__ void k_permute(const int* __restrict__ eidp, const int* __restrict__ src,
                          const float* __restrict__ edge_attr,
                          int* __restrict__ srcp, __half* __restrict__ eap) {
  int i = blockIdx.x * 256 + threadIdx.x;   // grid covers E exactly
  int e = eidp[i];
  srcp[i] = src[e] * 64;                    // pre-scaled half2 index
  const float4* ea4 = reinterpret_cast<const float4*>(edge_attr) + e * 4;
  float4 a0 = ea4[0], a1 = ea4[1], a2 = ea4[2], a3 = ea4[3];
  __half2* o = reinterpret_cast<__half2*>(eap + (long long)i * 16);
  o[0] = __floats2half2_rn(a0.x, a0.y);
  o[1] = __floats2half2_rn(a0.z, a0.w);
  o[2] = __floats2half2_rn(a1.x, a1.y);
  o[3] = __floats2half2_rn(a1.z, a1.w);
  o[4] = __floats2half2_rn(a2.x, a2.y);
  o[5] = __floats2half2_rn(a2.z, a2.w);
  o[6] = __floats2half2_rn(a3.x, a3.y);
  o[7] = __floats2half2_rn(a3.z, a3.w);
}

// ---------------------------------------------------------------------------
// CSR aggregation, atomic-free, LDS-free, 32-bit indexing, software-pipelined.
// One 64-lane wave per dst node (2 adjacent cols/lane). We panel in registers.
// Edge metadata (srcp, eap) is wave-uniform -> scalar loads; groups of 4 edges
// are double-buffered (load group B while computing group A) to hide latency.
// hpa16[d] = h16[d] + sum_{e in in(d)} relu(h16[src[e]] + ea[e] @ We + be)
__global__ __launch_bounds__(256) void k_agg(
    const __half* __restrict__ eap, const float* __restrict__ We,
    const float* __restrict__ be, const int* __restrict__ off,
    const int* __restrict__ srcp, const __half* __restrict__ h16,
    __half* __restrict__ hpa16, int d0) {
  int tid = threadIdx.x;
  int lane = tid & 63;
  int c0 = lane * 2;
  f16x2 wc0[8], wc1[8];
#pragma unroll
  for (int kk = 0; kk < 8; ++kk) {
    f16x2 w0, w1;
    w0[0] = (_Float16)We[(2 * kk) * 128 + c0];
    w0[1] = (_Float16)We[(2 * kk + 1) * 128 + c0];
    w1[0] = (_Float16)We[(2 * kk) * 128 + c0 + 1];
    w1[1] = (_Float16)We[(2 * kk + 1) * 128 + c0 + 1];
    wc0[kk] = w0; wc1[kk] = w1;
  }
  float2 bev = reinterpret_cast<const float2*>(be)[lane];
  int d = d0 + blockIdx.x * 4 + (tid >> 6);
  int j0 = off[d], j1 = off[d + 1];
  const __half2* h2 = reinterpret_cast<const __half2*>(h16);
  const int4* e4 = reinterpret_cast<const int4*>(eap);
  float a0 = 0.f, a1 = 0.f, b0 = 0.f, b1 = 0.f;
  float p0 = 0.f, p1 = 0.f, q0 = 0.f, q1 = 0.f;

#define FD(U, W, ACC) ACC = __builtin_amdgcn_fdot2(__builtin_bit_cast(f16x2, U), W, ACC, false)
#define COMP1(LOk, HIk, HVk, A0, A1) do {                                      \
    float ev0_ = bev.x, ev1_ = bev.y;                                          \
    FD(LOk.x, wc0[0], ev0_); FD(LOk.x, wc1[0], ev1_);                          \
    FD(LOk.y, wc0[1], ev0_); FD(LOk.y, wc1[1], ev1_);                          \
    FD(LOk.z, wc0[2], ev0_); FD(LOk.z, wc1[2], ev1_);                          \
    FD(LOk.w, wc0[3], ev0_); FD(LOk.w, wc1[3], ev1_);                          \
    FD(HIk.x, wc0[4], ev0_); FD(HIk.x, wc1[4], ev1_);                          \
    FD(HIk.y, wc0[5], ev0_); FD(HIk.y, wc1[5], ev1_);                          \
    FD(HIk.z, wc0[6], ev0_); FD(HIk.z, wc1[6], ev1_);                          \
    FD(HIk.w, wc0[7], ev0_); FD(HIk.w, wc1[7], ev1_);                          \
    A0 += fmaxf(__low2float(HVk) + ev0_, 0.f);                                 \
    A1 += fmaxf(__high2float(HVk) + ev1_, 0.f);                                \
  } while (0)
#define LOADG(S, LO, HI, HV, BASE) do {                                        \
    _Pragma("unroll")                                                          \
    for (int k_ = 0; k_ < 4; ++k_) {                                           \
      S[k_] = srcp[(BASE) + k_];                                               \
      LO[k_] = e4[2 * ((BASE) + k_)];                                          \
      HI[k_] = e4[2 * ((BASE) + k_) + 1];                                      \
    }                                                                          \
    _Pragma("unroll")                                                          \
    for (int k_ = 0; k_ < 4; ++k_) HV[k_] = h2[S[k_] + lane];                  \
  } while (0)
#define COMPG(LO, HI, HV) do {                                                 \
    COMP1(LO[0], HI[0], HV[0], a0, a1);                                        \
    COMP1(LO[1], HI[1], HV[1], b0, b1);                                        \
    COMP1(LO[2], HI[2], HV[2], p0, p1);                                        \
    COMP1(LO[3], HI[3], HV[3], q0, q1);                                        \
  } while (0)

  int j = j0;
  if (j + 3 < j1) {
    int sA[4], sB[4];
    int4 loA[4], hiA[4], loB[4], hiB[4];
    __half2 hvA[4], hvB[4];
    LOADG(sA, loA, hiA, hvA, j);
    j += 4;
    bool curA = true;
    while (j + 3 < j1) {
      if (curA) { LOADG(sB, loB, hiB, hvB, j); COMPG(loA, hiA, hvA); }
      else      { LOADG(sA, loA, hiA, hvA, j); COMPG(loB, hiB, hvB); }
      curA = !curA;
      j += 4;
    }
    if (curA) COMPG(loA, hiA, hvA);
    else      COMPG(loB, hiB, hvB);
  }
  for (; j < j1; ++j) {
    int s_ = srcp[j];
    int4 lo_ = e4[2 * j], hi_ = e4[2 * j + 1];
    __half2 hv_ = h2[s_ + lane];
    COMP1(lo_, hi_, hv_, a0, a1);
  }
#undef LOADG
#undef COMPG
#undef COMP1
#undef FD
  a0 += b0 + p0 + q0; a1 += b1 + p1 + q1;
  int di = d * 64 + lane;
  __half2 hd = h2[di];
  reinterpret_cast<__half2*>(hpa16)[di] =
      __floats2half2_rn(__low2float(hd) + a0, __high2float(hd) + a1);
}

// ---------------------------------------------------------------------------
// fp16 MFMA GEMM, K=128 fixed. C[M x ldc] fp32 (or fp16 when OUT_F16).
// A [M][128] f16 row-major; Bt [ldc][128] f16 with Bt[c][k] = W[k][c].
// Block: 64 rows x 128 cols, 4 waves in 2x2, wave tile 32x64.
// A is read DIRECTLY global->VGPR (its layout already matches the fragment);
// only B goes through LDS (35 KB). A reads may run past row M-1 into adjacent
// workspace (valid memory); garbage rows are never stored (row-local MFMA).
// STATS: fused column sum/sumsq -> atomicAdd into stats[0:ldc], stats[ldc:2ldc].
template<bool HAS_BIAS, bool HAS_ROWBIAS, bool OUT_F16, bool STATS>
__global__ __launch_bounds__(256) void k_mgemm(
    const __half* __restrict__ A, const __half* __restrict__ Bt,
    const float* __restrict__ bias, const float* __restrict__ bias2,
    const float* __restrict__ rowbias, const int* __restrict__ batch,
    float* __restrict__ Cf, __half* __restrict__ Ch,
    float* __restrict__ stats, int ldc, int M) {
  __shared__ _Float16 Bsh[128][136];   // +8 pad: row stride 272 B
  int tid = threadIdx.x;
  int m0 = blockIdx.x * 64;
  int c0 = blockIdx.y * 128;
  int wid = tid >> 6, lane = tid & 63;
  int wr = wid >> 1, wc = wid & 1;        // 2x2 wave grid, wave tile 32x64
  int lrow = lane & 15;
  int lk = (lane >> 4) * 8;

  // A fragments: direct global loads (issue before B staging for overlap)
  f16x8 af[4][2];
#pragma unroll
  for (int kk = 0; kk < 4; ++kk)
#pragma unroll
    for (int fm = 0; fm < 2; ++fm)
      af[kk][fm] = *reinterpret_cast<const f16x8*>(
          A + (m0 + wr * 32 + fm * 16 + lrow) * 128 + kk * 32 + lk);

  // stage B: 128 rows x 16 chunks = 2048 chunks
#pragma unroll
  for (int it = 0; it < 8; ++it) {
    int idx = it * 256 + tid;
    int r = idx >> 4, ck = idx & 15;
    f16x8 v = *reinterpret_cast<const f16x8*>(Bt + ((c0 + r) << 7) + ck * 8);
    *reinterpret_cast<f16x8*>(&Bsh[r][ck * 8]) = v;
  }
  __syncthreads();

  f32x4 acc[2][4];
#pragma unroll
  for (int fm = 0; fm < 2; ++fm)
#pragma unroll
    for (int fn = 0; fn < 4; ++fn) acc[fm][fn] = (f32x4){0.f, 0.f, 0.f, 0.f};

#pragma unroll
  for (int kk = 0; kk < 4; ++kk) {
    f16x8 bf[4];
#pragma unroll
    for (int fn = 0; fn < 4; ++fn)
      bf[fn] = *reinterpret_cast<const f16x8*>(&Bsh[wc * 64 + fn * 16 + lrow][kk * 32 + lk]);
#pragma unroll
    for (int fm = 0; fm < 2; ++fm)
#pragma unroll
      for (int fn = 0; fn < 4; ++fn)
        acc[fm][fn] = __builtin_amdgcn_mfma_f32_16x16x32_f16(af[kk][fm], bf[fn], acc[fm][fn], 0, 0, 0);
  }

  // epilogue (+ optional fused column stats)
  float ss[4], ss2[4];
#pragma unroll
  for (int fn = 0; fn < 4; ++fn) { ss[fn] = 0.f; ss2[fn] = 0.f; }
#pragma unroll
  for (int fn = 0; fn < 4; ++fn) {
    int col = c0 + wc * 64 + fn * 16 + lrow;
    float bb = HAS_BIAS ? bias[col] : 0.f;
    if (HAS_BIAS && bias2 != nullptr) bb += bias2[col];
#pragma unroll
    for (int fm = 0; fm < 2; ++fm) {
      int grb = m0 + wr * 32 + fm * 16 + (lane >> 4) * 4;
#pragma unroll
      for (int j = 0; j < 4; ++j) {
        int gr = grb + j;
        if (gr < M) {
          float v = acc[fm][fn][j] + bb;
          if (HAS_ROWBIAS)
            v += rowbias[batch[gr] * ldc + col];
          if (STATS) { ss[fn] += v; ss2[fn] += v * v; }
          if (OUT_F16)
            Ch[(long long)gr * ldc + col] = __float2half(v);
          else
            Cf[(long long)gr * ldc + col] = v;
        }
      }
    }
  }
  if (STATS) {
    __shared__ float sred[2][4][4][16];   // [s|s2][wid][fn][lrow]
#pragma unroll
    for (int fn = 0; fn < 4; ++fn) {
      float s = ss[fn], s2 = ss2[fn];
      s += __shfl_xor(s, 16);  s += __shfl_xor(s, 32);
      s2 += __shfl_xor(s2, 16); s2 += __shfl_xor(s2, 32);
      if (lane < 16) { sred[0][wid][fn][lane] = s; sred[1][wid][fn][lane] = s2; }
    }
    __syncthreads();
    if (wr == 0 && lane < 16) {           // waves 0,1 combine with waves 2,3
#pragma unroll
      for (int fn = 0; fn < 4; ++fn) {
        int col = c0 + wc * 64 + fn * 16 + lane;
        atomicAdd(&stats[col],       sred[0][wid][fn][lane] + sred[0][wid + 2][fn][lane]);
        atomicAdd(&stats[ldc + col], sred[1][wid][fn][lane] + sred[1][wid + 2][fn][lane]);
      }
    }
  }
}

// ---------------------------------------------------------------------------
// Generic fp32 vector GEMM for the small (G-row) matmuls.
// STATS: fused column sum/sumsq into stats[0:128], stats[ldw:ldw+128] via LDS.
template<int K, bool HAS_BIAS, bool HAS_ROWBIAS, bool RELU, bool STATS>
__global__ __launch_bounds__(256) void k_gemm(
    const float* __restrict__ A1,
    const float* __restrict__ W, int ldw,
    const float* __restrict__ bias,
    const float* __restrict__ rowbias, const int* __restrict__ batch,
    float* __restrict__ C, float* __restrict__ stats, int M) {
  __shared__ float As[32 * K];
  constexpr int K4 = K / 4;
  int tid = threadIdx.x;
  int m0 = blockIdx.x * 32;
#pragma unroll
  for (int it = 0; it < K / 32; ++it) {
    int e4 = it * 256 + tid;
    int r = e4 / K4;
    int k4 = e4 % K4;
    int gr = m0 + r;
    float4 v = make_float4(0.f, 0.f, 0.f, 0.f);
    if (gr < M) v = reinterpret_cast<const float4*>(A1)[(long long)gr * K4 + k4];
    reinterpret_cast<float4*>(As)[e4] = v;
  }
  __shared__ float cs[128], cs2[128];
  if (STATS && tid < 128) { cs[tid] = 0.f; cs2[tid] = 0.f; }
  __syncthreads();

  int cg = tid & 31;
  int rg = tid >> 5;
  int col = blockIdx.y * 128 + cg * 4;
  float4 acc[4];
#pragma unroll
  for (int j = 0; j < 4; ++j) acc[j] = make_float4(0.f, 0.f, 0.f, 0.f);
  const float4* W4 = reinterpret_cast<const float4*>(W);
  const float4* As4 = reinterpret_cast<const float4*>(As);
#pragma unroll 8
  for (int k = 0; k < K; k += 4) {
    float4 w0 = W4[((k + 0) * ldw + col) >> 2];
    float4 w1 = W4[((k + 1) * ldw + col) >> 2];
    float4 w2 = W4[((k + 2) * ldw + col) >> 2];
    float4 w3 = W4[((k + 3) * ldw + col) >> 2];
#pragma unroll
    for (int j = 0; j < 4; ++j) {
      float4 a = As4[(rg + j * 8) * K4 + (k >> 2)];
      acc[j].x += a.x * w0.x + a.y * w1.x + a.z * w2.x + a.w * w3.x;
      acc[j].y += a.x * w0.y + a.y * w1.y + a.z * w2.y + a.w * w3.y;
      acc[j].z += a.x * w0.z + a.y * w1.z + a.z * w2.z + a.w * w3.z;
      acc[j].w += a.x * w0.w + a.y * w1.w + a.z * w2.w + a.w * w3.w;
    }
  }
  float4 bb = make_float4(0.f, 0.f, 0.f, 0.f);
  if (HAS_BIAS) bb = reinterpret_cast<const float4*>(bias)[blockIdx.y * 32 + cg];
  float ps[4] = {0.f, 0.f, 0.f, 0.f}, ps2[4] = {0.f, 0.f, 0.f, 0.f};
#pragma unroll
  for (int j = 0; j < 4; ++j) {
    int gr = m0 + rg + j * 8;
    if (gr < M) {
      float4 v = acc[j];
      v.x += bb.x; v.y += bb.y; v.z += bb.z; v.w += bb.w;
      if (HAS_ROWBIAS) {
        int b = batch[gr];
        float4 rb = reinterpret_cast<const float4*>(rowbias)[((long long)b * ldw + col) >> 2];
        v.x += rb.x; v.y += rb.y; v.z += rb.z; v.w += rb.w;
      }
      if (RELU) {
        v.x = fmaxf(v.x, 0.f); v.y = fmaxf(v.y, 0.f);
        v.z = fmaxf(v.z, 0.f); v.w = fmaxf(v.w, 0.f);
      }
      if (STATS) {
        ps[0] += v.x; ps2[0] += v.x * v.x;
        ps[1] += v.y; ps2[1] += v.y * v.y;
        ps[2] += v.z; ps2[2] += v.z * v.z;
        ps[3] += v.w; ps2[3] += v.w * v.w;
      }
      reinterpret_cast<float4*>(C)[((long long)gr * ldw + col) >> 2] = v;
    }
  }
  if (STATS) {
#pragma unroll
    for (int jc = 0; jc < 4; ++jc) {
      atomicAdd(&cs[cg * 4 + jc], ps[jc]);
      atomicAdd(&cs2[cg * 4 + jc], ps2[jc]);
    }
    __syncthreads();
    if (tid < 128) {
      atomicAdd(&stats[blockIdx.y * 128 + tid], cs[tid]);
      atomicAdd(&stats[ldw + blockIdx.y * 128 + tid], cs2[tid]);
    }
  }
}

// ---------------------------------------------------------------------------
// h16 = (half) relu(bn(z16)); half2 lanes, grid = N*64/256 = 12500 exact
__global__ void k_bn16(const __half* __restrict__ X16, const float* __restrict__ stats,
                       const float* __restrict__ gam, const float* __restrict__ beta,
                       __half* __restrict__ out16, float invM) {
  int i2 = blockIdx.x * 256 + threadIdx.x;
  int c = (i2 & 63) * 2;
  __half2 xv = reinterpret_cast<const __half2*>(X16)[i2];
  float m0 = stats[c] * invM;
  float v0 = stats[128 + c] * invM - m0 * m0;
  float m1 = stats[c + 1] * invM;
  float v1 = stats[128 + c + 1] * invM - m1 * m1;
  float r0 = fmaxf((__low2float(xv) - m0) * rsqrtf(v0 + EPS) * gam[c] + beta[c], 0.f);
  float r1 = fmaxf((__high2float(xv) - m1) * rsqrtf(v1 + EPS) * gam[c + 1] + beta[c + 1], 0.f);
  reinterpret_cast<__half2*>(out16)[i2] = __floats2half2_rn(r0, r1);
}

// pooled[g][c] = sum over graph-g rows of relu(bn(z2_16[r][c])).
// Per-graph blocks via gstart; 4-way row-parallel (512 threads) + LDS reduce.
__global__ void k_pool(const __half* __restrict__ z2_16, const float* __restrict__ stats,
                       const float* __restrict__ gam, const float* __restrict__ beta,
                       const int* __restrict__ gstart, float* __restrict__ pooled) {
  int tid = threadIdx.x;            // 512
  int rsub = tid >> 7;              // 0..3
  int cl = tid & 127;
  int g = blockIdx.x;
  int c = blockIdx.y * 128 + cl;    // grid (G,2)
  const float invM = 1.f / (float)N;
  float mean = stats[c] * invM;
  float var = stats[256 + c] * invM - mean * mean;
  float scale = rsqrtf(var + EPS) * gam[c];
  float shift = beta[c] - mean * scale;
  int r0 = gstart[g], r1 = gstart[g + 1];
  float acc = 0.f;
  for (int r = r0 + rsub; r < r1; r += 4) {
    float v = __half2float(z2_16[(long long)r * 256 + c]);
    acc += fmaxf(v * scale + shift, 0.f);
  }
  __shared__ float sred[512];
  sred[tid] = acc;
  __syncthreads();
  if (rsub == 0)
    pooled[g * 256 + c] = sred[cl] + sred[128 + cl] + sred[256 + cl] + sred[384 + cl];
}

// vn = relu(bn(zvn)); also write into hg concat buffer at layer offset
__global__ void k_vnapply(const float* __restrict__ zvn, const float* __restrict__ stats,
                          const float* __restrict__ gam, const float* __restrict__ beta,
                          float* __restrict__ vn, float* __restrict__ hgbuf, int layer) {
  int idx = blockIdx.x * 256 + threadIdx.x;  // G*H = 65536
  int c = idx & 127;
  int g = idx >> 7;
  const float invM = 1.f / (float)G;
  float mean = stats[c] * invM;
  float var = stats[128 + c] * invM - mean * mean;
  float v = fmaxf((zvn[idx] - mean) * rsqrtf(var + EPS) * gam[c] + beta[c], 0.f);
  vn[idx] = v;
  hgbuf[g * 384 + layer * 128 + c] = v;
}

// out[g] = hg2[g] @ pred_W2 + b2   (one wave per graph)
__global__ void k_pred2(const float* __restrict__ hg2, const float* __restrict__ W2,
                        const float* __restrict__ b2, float* __restrict__ out) {
  int g = blockIdx.x;
  int lane = threadIdx.x;
  float s = 0.f;
  for (int k = lane; k < 384; k += 64) s += hg2[g * 384 + k] * W2[k];
  for (int off = 32; off; off >>= 1) s += __shfl_down(s, off);
  if (lane == 0) out[g] = s + b2[0];
}

// ---------------------------------------------------------------------------
extern "C" void kernel_launch(void* const* d_in, const int* in_sizes, int n_in,
                              void* d_out, int out_size, void* d_ws, size_t ws_size,
                              hipStream_t stream) {
  const float* x         = (const float*)d_in[0];
  const float* edge_attr = (const float*)d_in[1];
  const float* atom_W    = (const float*)d_in[2];
  const float* atom_b    = (const float*)d_in[3];
  const float* vn_emb    = (const float*)d_in[4];
  const float* conv_We   = (const float*)d_in[5];
  const float* conv_be   = (const float*)d_in[6];
  const float* conv_W    = (const float*)d_in[7];
  const float* conv_b    = (const float*)d_in[8];
  const float* conv_g    = (const float*)d_in[9];
  const float* conv_beta = (const float*)d_in[10];
  const float* vn1_W     = (const float*)d_in[11];
  const float* vn1_b     = (const float*)d_in[12];
  const float* vn1_g     = (const float*)d_in[13];
  const float* vn1_beta  = (const float*)d_in[14];
  const float* vn2_W     = (const float*)d_in[15];
  const float* vn2_b     = (const float*)d_in[16];
  const float* vn2_g     = (const float*)d_in[17];
  const float* vn2_beta  = (const float*)d_in[18];
  const float* pred_W1   = (const float*)d_in[19];
  const float* pred_b1   = (const float*)d_in[20];
  const float* pred_W2   = (const float*)d_in[21];
  const float* pred_b2   = (const float*)d_in[22];
  const int*   eidx      = (const int*)d_in[23];
  const int*   batch     = (const int*)d_in[24];
  const int* src = eidx;
  const int* dst = eidx + E;

  // Workspace layout (units: 4-byte slots). Total ~24.1M slots = ~96.5 MB.
  float* ws    = (float*)d_ws;
  __half* h16  = (__half*)ws;                  // N*128 halves
  float* bufB  = ws + NH / 2;                  // 2*NH slots
  __half* hpa16= (__half*)bufB;                // N*128 halves  [B 0 .. NH/2)
  __half* z16  = (__half*)(bufB + NH / 2);     // N*128 halves  [B NH/2 .. NH)
  __half* x16  = z16;                          // alias (dead before conv gemm)
  __half* z2_16= (__half*)(bufB + NH);         // N*256 halves  [B NH .. 2NH)
  float* smallz= bufB + 2 * NH;
  float* U     = smallz;                       // G*256
  float* pooled= U + G * 256;                  // G*256
  float* zvn   = pooled + G * 256;             // G*128
  float* vn    = zvn + G * 128;                // G*128
  float* hgbuf = vn + G * 128;                 // G*384
  float* hg2   = hgbuf + G * 384;              // G*384
  float* statsz= hg2 + G * 384;                // 3*1024 (per-layer slices)
  int*   gstart= (int*)(statsz + 3 * 1024);    // G+1 (pad 516)
  __half* atomWt = (__half*)(gstart + 516);    // 128*128 halves
  __half* convWt = atomWt + 16384;             // 3 * 128*128
  __half* z2Wt   = convWt + 3 * 16384;         // 3 * 256*128
  int*  off    = (int*)(z2Wt + 3 * 32768);     // N+1 (padded 50002)
  int*  srcp   = off + 50002;                  // E ints (dst-sorted src*64)
  __half* eap  = (__half*)(srcp + E);          // E*16 halves (dst-sorted fp16 ea)
  // CSR build temporaries (dead before first k_agg) alias bufB:
  int* cnt  = (int*)bufB;                      // N
  int* cur  = cnt + N;                         // N
  int* bsum = cur + N;                         // NB_SCAN
  int* eidp = cur + N + 256;                   // E (dst-sorted edge ids)

  dim3 b256(256);

  // ---- CSR build (once; edge_index identical across layers) ----
  hipMemsetAsync(cnt, 0, (size_t)(2 * N + NB_SCAN) * 4, stream);  // cnt+cur+bsum
  hipMemsetAsync(statsz, 0, 3 * 1024 * 4, stream);
  k_hist<<<E / 256, b256, 0, stream>>>(dst, cnt);
  k_scan_block<<<NB_SCAN, b256, 0, stream>>>(cnt, off, bsum);
  k_scan_bsum<<<1, b256, 0, stream>>>(bsum);
  k_scan_add<<<NB_SCAN, b256, 0, stream>>>(off, bsum);
  k_scatter_idx<<<E / 256, b256, 0, stream>>>(dst, off, cur, eidp);
  k_permute<<<E / 256, b256, 0, stream>>>(eidp, src, edge_attr, srcp, eap);
  k_gstart<<<1, G, 0, stream>>>(batch, gstart);

  k_init_vn<<<G * 128 / 256, b256, 0, stream>>>(vn_emb, vn);

  // ---- weight/input fp16 prep ----
  k_tof16<<<(N * 128 / 4 + 255) / 256, b256, 0, stream>>>(x, x16, N * 128 / 4);
  k_wt<<<dim3(64, 1), b256, 0, stream>>>(atom_W, atomWt, 128, 0, 128, 0, 0);
  k_wt<<<dim3(64, 3), b256, 0, stream>>>(conv_W, convWt, 128, 0, 128, 16384, 16384);
  k_wt<<<dim3(128, 3), b256, 0, stream>>>(vn1_W, z2Wt, 256, 128, 256, 65536, 32768);

  // h16 = x16 @ atom_W + (atom_b + vn_emb)   (layer-0 addvn folded)
  k_mgemm<true, false, true, false><<<dim3(782, 1), b256, 0, stream>>>(
      x16, atomWt, atom_b, vn_emb, nullptr, nullptr, nullptr, h16, nullptr, 128, N);

  for (int i = 0; i < 3; ++i) {
    float* SZ = statsz + i * 1024;   // conv: +0 (256), z2: +256 (512), zvn: +768 (256)
    if (i > 0) k_addvn16<<<12500, b256, 0, stream>>>(h16, vn, batch);
    // hpa16 = h16 + sum_in relu(h16[src] + ea@We + be)  (2 half-grid dispatches)
    k_agg<<<6250, b256, 0, stream>>>(eap, conv_We + i * 2048, conv_be + i * 128,
                                     off, srcp, h16, hpa16, 0);
    k_agg<<<6250, b256, 0, stream>>>(eap, conv_We + i * 2048, conv_be + i * 128,
                                     off, srcp, h16, hpa16, 25000);
    // z16 = hpa16 @ conv_W[i] + conv_b[i]   (MFMA, fp16 out, fused stats)
    k_mgemm<true, false, true, true><<<dim3(782, 1), b256, 0, stream>>>(
        hpa16, convWt + i * 16384, conv_b + i * 128, nullptr, nullptr, nullptr,
        nullptr, z16, SZ, 128, N);
    // h16 = relu(bn(z16))
    k_bn16<<<12500, b256, 0, stream>>>(z16, SZ, conv_g + i * 128, conv_beta + i * 128,
                                       h16, 1.f / (float)N);
    // U = vn @ vn1_W[i][:128,:] + vn1_b[i]   (512 distinct rows of vn[batch])
    k_gemm<128, true, false, false, false><<<dim3(16, 2), b256, 0, stream>>>(
        vn, vn1_W + i * 256 * 256, 256, vn1_b + i * 256, nullptr, nullptr, U, nullptr, G);
    // z2_16 = h16 @ vn1_W[i][128:,:] + U[batch]   (MFMA, fp16 out, fused stats)
    k_mgemm<false, true, true, true><<<dim3(782, 2), b256, 0, stream>>>(
        h16, z2Wt + i * 32768, nullptr, nullptr, U, batch, nullptr, z2_16,
        SZ + 256, 256, N);
    // pooled[g] = sum relu(bn(z2_16))   (per-graph, 4-way row-parallel)
    k_pool<<<dim3(G, 2), dim3(512), 0, stream>>>(
        z2_16, SZ + 256, vn1_g + i * 256, vn1_beta + i * 256, gstart, pooled);
    // zvn = pooled @ vn2_W[i] + vn2_b[i]  (fused stats)
    k_gemm<256, true, false, false, true><<<dim3(16, 1), b256, 0, stream>>>(
        pooled, vn2_W + i * 256 * 128, 128, vn2_b + i * 128, nullptr, nullptr,
        zvn, SZ + 768, G);
    k_vnapply<<<G * 128 / 256, b256, 0, stream>>>(
        zvn, SZ + 768, vn2_g + i * 128, vn2_beta + i * 128, vn, hgbuf, i);
  }
  // hg2 = relu(hgbuf @ pred_W1 + pred_b1)
  k_gemm<384, true, false, true, false><<<dim3(16, 3), b256, 0, stream>>>(
      hgbuf, pred_W1, 384, pred_b1, nullptr, nullptr, hg2, nullptr, G);
  k_pred2<<<G, 64, 0, stream>>>(hg2, pred_W2, pred_b2, (float*)d_out);
}

// Round 10
// 1210.136 us; speedup vs baseline: 1.1476x; 1.1476x over previous
//
#include <hip/hip_runtime.h>
#include <hip/hip_fp16.h>

// Problem constants (fixed by the reference)
constexpr int N = 50000;
constexpr int E = 800000;
constexpr int G = 512;
constexpr int H = 128;
constexpr long long NH = (long long)N * H;   // 6,400,000 elements
constexpr float EPS = 1e-5f;
constexpr int NB_SCAN = 196;                 // ceil(50000/256)

typedef _Float16 f16x8 __attribute__((ext_vector_type(8)));
typedef _Float16 f16x2 __attribute__((ext_vector_type(2)));
typedef float f32x4 __attribute__((ext_vector_type(4)));

// ---------------------------------------------------------------------------
// vn[g][c] = vn_emb[c]
__global__ void k_init_vn(const float* __restrict__ vn_emb, float* __restrict__ vn) {
  int idx = blockIdx.x * 256 + threadIdx.x;   // G*H = 65536 exactly
  vn[idx] = vn_emb[idx & 127];
}

// fp32 -> fp16 bulk convert (float4 -> half2 x2), grid covers n4 exactly
__global__ void k_tof16(const float* __restrict__ in, __half* __restrict__ out, int n4) {
  int i = blockIdx.x * 256 + threadIdx.x;
  if (i >= n4) return;
  float4 v = reinterpret_cast<const float4*>(in)[i];
  __half2* o = reinterpret_cast<__half2*>(out);
  o[i * 2]     = __floats2half2_rn(v.x, v.y);
  o[i * 2 + 1] = __floats2half2_rn(v.z, v.w);
}

// Wt[c][k] = (half) W[(row0+k)*ldw + c], K=128 fixed; one layer per blockIdx.y
__global__ void k_wt(const float* __restrict__ W, __half* __restrict__ Wt,
                     int ldw, int row0, int cols, long long wstride, int wtstride) {
  const float* Wl = W + (long long)blockIdx.y * wstride;
  __half* Wtl = Wt + (long long)blockIdx.y * wtstride;
  int idx = blockIdx.x * 256 + threadIdx.x;   // cols*128, exact multiple of 256
  int k = idx & 127, c = idx >> 7;
  Wtl[c * 128 + k] = __float2half(Wl[(long long)(row0 + k) * ldw + c]);
}

// h16[r][:] += vn[batch[r]][:]  (half2 lanes, grid = N*64/256 = 12500 exact)
__global__ void k_addvn16(__half* __restrict__ h16, const float* __restrict__ vn,
                          const int* __restrict__ batch) {
  int i2 = blockIdx.x * 256 + threadIdx.x;
  int r = i2 >> 6;
  int b = batch[r];
  __half2 hv = reinterpret_cast<__half2*>(h16)[i2];
  float2 vv = reinterpret_cast<const float2*>(vn)[(b << 6) + (i2 & 63)];
  reinterpret_cast<__half2*>(h16)[i2] =
      __floats2half2_rn(__low2float(hv) + vv.x, __high2float(hv) + vv.y);
}

// gstart[g] = lower_bound(batch, g); gstart[G] = N  (batch is sorted)
__global__ void k_gstart(const int* __restrict__ batch, int* __restrict__ gstart) {
  int g = threadIdx.x;   // one block of 512
  int lo = 0, hi = N;
  while (lo < hi) { int mid = (lo + hi) >> 1; if (batch[mid] < g) lo = mid + 1; else hi = mid; }
  gstart[g] = lo;
  if (g == 0) gstart[G] = N;
}

// ---------------------------------------------------------------------------
// CSR build: histogram -> 2-level exclusive scan -> idx-scatter -> gather-permute.
// idx-scatter randomly writes ONLY the 4B edge id; permute then reads edge_attr
// as full 64B lines (no partial-line RMW) and streams eap/srcp out coalesced.
__global__ void k_hist(const int* __restrict__ dst, int* __restrict__ cnt) {
  int e = blockIdx.x * 256 + threadIdx.x;   // grid covers E exactly
  atomicAdd(&cnt[dst[e]], 1);
}

__global__ void k_scan_block(const int* __restrict__ cnt, int* __restrict__ off,
                             int* __restrict__ bsum) {
  __shared__ int s[256];
  int idx = blockIdx.x * 256 + threadIdx.x;
  int v = (idx < N) ? cnt[idx] : 0;
  s[threadIdx.x] = v;
  __syncthreads();
  for (int o = 1; o < 256; o <<= 1) {
    int t = (threadIdx.x >= o) ? s[threadIdx.x - o] : 0;
    __syncthreads();
    s[threadIdx.x] += t;
    __syncthreads();
  }
  if (idx < N) off[idx + 1] = s[threadIdx.x];
  if (threadIdx.x == 255) bsum[blockIdx.x] = s[255];
  if (idx == 0) off[0] = 0;
}

__global__ void k_scan_bsum(int* __restrict__ bsum) {   // single block
  __shared__ int s[256];
  int v = (threadIdx.x < NB_SCAN) ? bsum[threadIdx.x] : 0;
  s[threadIdx.x] = v;
  __syncthreads();
  for (int o = 1; o < 256; o <<= 1) {
    int t = (threadIdx.x >= o) ? s[threadIdx.x - o] : 0;
    __syncthreads();
    s[threadIdx.x] += t;
    __syncthreads();
  }
  if (threadIdx.x < NB_SCAN) bsum[threadIdx.x] = s[threadIdx.x];  // inclusive
}

__global__ void k_scan_add(int* __restrict__ off, const int* __restrict__ bsum) {
  int idx = blockIdx.x * 256 + threadIdx.x;
  if (idx < N && blockIdx.x > 0) off[idx + 1] += bsum[blockIdx.x - 1];
}

__global__ void k_scatter_idx(const int* __restrict__ dst, const int* __restrict__ off,
                              int* __restrict__ cur, int* __restrict__ eidp) {
  int e = blockIdx.x * 256 + threadIdx.x;   // grid covers E exactly
  int d = dst[e];
  int p = off[d] + atomicAdd(&cur[d], 1);
  eidp[p] = e;
}

__global__ void k_permute(const int* __restrict__ eidp, const int* __restrict__ src,
                          const float* __restrict__ edge_attr,
                          int* __restrict__ srcp, __half* __restrict__ eap) {
  int i = blockIdx.x * 256 + threadIdx.x;   // grid covers E exactly
  int e = eidp[i];
  srcp[i] = src[e] * 64;                    // pre-scaled half2 index
  const float4* ea4 = reinterpret_cast<const float4*>(edge_attr) + e * 4;
  float4 a0 = ea4[0], a1 = ea4[1], a2 = ea4[2], a3 = ea4[3];
  __half2 h01 = __floats2half2_rn(a0.x, a0.y);
  __half2 h23 = __floats2half2_rn(a0.z, a0.w);
  __half2 h45 = __floats2half2_rn(a1.x, a1.y);
  __half2 h67 = __floats2half2_rn(a1.z, a1.w);
  __half2 h89 = __floats2half2_rn(a2.x, a2.y);
  __half2 hab = __floats2half2_rn(a2.z, a2.w);
  __half2 hcd = __floats2half2_rn(a3.x, a3.y);
  __half2 hef = __floats2half2_rn(a3.z, a3.w);
  int4 lo = make_int4(__builtin_bit_cast(int, h01), __builtin_bit_cast(int, h23),
                      __builtin_bit_cast(int, h45), __builtin_bit_cast(int, h67));
  int4 hi = make_int4(__builtin_bit_cast(int, h89), __builtin_bit_cast(int, hab),
                      __builtin_bit_cast(int, hcd), __builtin_bit_cast(int, hef));
  int4* o = reinterpret_cast<int4*>(eap + (long long)i * 16);
  o[0] = lo;
  o[1] = hi;
}

// ---------------------------------------------------------------------------
// CSR aggregation, atomic-free, LDS-free, all-32-bit indexing. One 64-lane
// wave per dst node (2 adjacent cols/lane). We panel in registers (fdot2).
// 4 independent accumulator chains; NO cross-group double-buffer (round-9
// lesson: +24 VGPR halved occupancy and regressed — TLP does the hiding).
// hpa16[d] = h16[d] + sum_{e in in(d)} relu(h16[src[e]] + ea[e] @ We + be)
__global__ __launch_bounds__(256) void k_agg(
    const __half* __restrict__ eap, const float* __restrict__ We,
    const float* __restrict__ be, const int* __restrict__ off,
    const int* __restrict__ srcp, const __half* __restrict__ h16,
    __half* __restrict__ hpa16, int d0) {
  int tid = threadIdx.x;
  int lane = tid & 63;
  int c0 = lane * 2;
  f16x2 wc0[8], wc1[8];
#pragma unroll
  for (int kk = 0; kk < 8; ++kk) {
    f16x2 w0, w1;
    w0[0] = (_Float16)We[(2 * kk) * 128 + c0];
    w0[1] = (_Float16)We[(2 * kk + 1) * 128 + c0];
    w1[0] = (_Float16)We[(2 * kk) * 128 + c0 + 1];
    w1[1] = (_Float16)We[(2 * kk + 1) * 128 + c0 + 1];
    wc0[kk] = w0; wc1[kk] = w1;
  }
  float2 bev = reinterpret_cast<const float2*>(be)[lane];
  int d = d0 + blockIdx.x * 4 + (tid >> 6);
  int j0 = off[d], j1 = off[d + 1];
  const __half2* h2 = reinterpret_cast<const __half2*>(h16);
  const int4* e4 = reinterpret_cast<const int4*>(eap);
  float a0 = 0.f, a1 = 0.f, b0 = 0.f, b1 = 0.f;
  float p0 = 0.f, p1 = 0.f, q0 = 0.f, q1 = 0.f;
  int j = j0;
#define EDGE(J, A0, A1) do {                                                   \
    int s_ = srcp[(J)];                                                        \
    __half2 hv_ = h2[s_ + lane];                                               \
    int4 lo_ = e4[2 * (J)], hi_ = e4[2 * (J) + 1];                             \
    float ev0_ = bev.x, ev1_ = bev.y;                                          \
    ev0_ = __builtin_amdgcn_fdot2(__builtin_bit_cast(f16x2, lo_.x), wc0[0], ev0_, false); \
    ev1_ = __builtin_amdgcn_fdot2(__builtin_bit_cast(f16x2, lo_.x), wc1[0], ev1_, false); \
    ev0_ = __builtin_amdgcn_fdot2(__builtin_bit_cast(f16x2, lo_.y), wc0[1], ev0_, false); \
    ev1_ = __builtin_amdgcn_fdot2(__builtin_bit_cast(f16x2, lo_.y), wc1[1], ev1_, false); \
    ev0_ = __builtin_amdgcn_fdot2(__builtin_bit_cast(f16x2, lo_.z), wc0[2], ev0_, false); \
    ev1_ = __builtin_amdgcn_fdot2(__builtin_bit_cast(f16x2, lo_.z), wc1[2], ev1_, false); \
    ev0_ = __builtin_amdgcn_fdot2(__builtin_bit_cast(f16x2, lo_.w), wc0[3], ev0_, false); \
    ev1_ = __builtin_amdgcn_fdot2(__builtin_bit_cast(f16x2, lo_.w), wc1[3], ev1_, false); \
    ev0_ = __builtin_amdgcn_fdot2(__builtin_bit_cast(f16x2, hi_.x), wc0[4], ev0_, false); \
    ev1_ = __builtin_amdgcn_fdot2(__builtin_bit_cast(f16x2, hi_.x), wc1[4], ev1_, false); \
    ev0_ = __builtin_amdgcn_fdot2(__builtin_bit_cast(f16x2, hi_.y), wc0[5], ev0_, false); \
    ev1_ = __builtin_amdgcn_fdot2(__builtin_bit_cast(f16x2, hi_.y), wc1[5], ev1_, false); \
    ev0_ = __builtin_amdgcn_fdot2(__builtin_bit_cast(f16x2, hi_.z), wc0[6], ev0_, false); \
    ev1_ = __builtin_amdgcn_fdot2(__builtin_bit_cast(f16x2, hi_.z), wc1[6], ev1_, false); \
    ev0_ = __builtin_amdgcn_fdot2(__builtin_bit_cast(f16x2, hi_.w), wc0[7], ev0_, false); \
    ev1_ = __builtin_amdgcn_fdot2(__builtin_bit_cast(f16x2, hi_.w), wc1[7], ev1_, false); \
    A0 += fmaxf(__low2float(hv_) + ev0_, 0.f);                                 \
    A1 += fmaxf(__high2float(hv_) + ev1_, 0.f);                                \
  } while (0)
  for (; j + 3 < j1; j += 4) {
    EDGE(j, a0, a1);
    EDGE(j + 1, b0, b1);
    EDGE(j + 2, p0, p1);
    EDGE(j + 3, q0, q1);
  }
  for (; j < j1; ++j) EDGE(j, a0, a1);
#undef EDGE
  a0 += b0 + p0 + q0; a1 += b1 + p1 + q1;
  int di = d * 64 + lane;
  __half2 hd = h2[di];
  reinterpret_cast<__half2*>(hpa16)[di] =
      __floats2half2_rn(__low2float(hd) + a0, __high2float(hd) + a1);
}

// ---------------------------------------------------------------------------
// fp16 MFMA GEMM, K=128 fixed. C[M x ldc] fp32 (or fp16 when OUT_F16).
// A [M][128] f16 row-major; Bt [ldc][128] f16 with Bt[c][k] = W[k][c].
// Block: 64 rows x 128 cols, 4 waves in 2x2, wave tile 32x64.
// A is read DIRECTLY global->VGPR (its layout already matches the fragment);
// only B goes through LDS (35 KB). A reads may run past row M-1 into adjacent
// workspace (valid memory); garbage rows are never stored (row-local MFMA).
// STATS: fused column sum/sumsq -> atomicAdd into stats[0:ldc], stats[ldc:2ldc].
template<bool HAS_BIAS, bool HAS_ROWBIAS, bool OUT_F16, bool STATS>
__global__ __launch_bounds__(256) void k_mgemm(
    const __half* __restrict__ A, const __half* __restrict__ Bt,
    const float* __restrict__ bias, const float* __restrict__ bias2,
    const float* __restrict__ rowbias, const int* __restrict__ batch,
    float* __restrict__ Cf, __half* __restrict__ Ch,
    float* __restrict__ stats, int ldc, int M) {
  __shared__ _Float16 Bsh[128][136];   // +8 pad: row stride 272 B
  int tid = threadIdx.x;
  int m0 = blockIdx.x * 64;
  int c0 = blockIdx.y * 128;
  int wid = tid >> 6, lane = tid & 63;
  int wr = wid >> 1, wc = wid & 1;        // 2x2 wave grid, wave tile 32x64
  int lrow = lane & 15;
  int lk = (lane >> 4) * 8;

  // A fragments: direct global loads (issue before B staging for overlap)
  f16x8 af[4][2];
#pragma unroll
  for (int kk = 0; kk < 4; ++kk)
#pragma unroll
    for (int fm = 0; fm < 2; ++fm)
      af[kk][fm] = *reinterpret_cast<const f16x8*>(
          A + (m0 + wr * 32 + fm * 16 + lrow) * 128 + kk * 32 + lk);

  // stage B: 128 rows x 16 chunks = 2048 chunks
#pragma unroll
  for (int it = 0; it < 8; ++it) {
    int idx = it * 256 + tid;
    int r = idx >> 4, ck = idx & 15;
    f16x8 v = *reinterpret_cast<const f16x8*>(Bt + ((c0 + r) << 7) + ck * 8);
    *reinterpret_cast<f16x8*>(&Bsh[r][ck * 8]) = v;
  }
  __syncthreads();

  f32x4 acc[2][4];
#pragma unroll
  for (int fm = 0; fm < 2; ++fm)
#pragma unroll
    for (int fn = 0; fn < 4; ++fn) acc[fm][fn] = (f32x4){0.f, 0.f, 0.f, 0.f};

#pragma unroll
  for (int kk = 0; kk < 4; ++kk) {
    f16x8 bf[4];
#pragma unroll
    for (int fn = 0; fn < 4; ++fn)
      bf[fn] = *reinterpret_cast<const f16x8*>(&Bsh[wc * 64 + fn * 16 + lrow][kk * 32 + lk]);
#pragma unroll
    for (int fm = 0; fm < 2; ++fm)
#pragma unroll
      for (int fn = 0; fn < 4; ++fn)
        acc[fm][fn] = __builtin_amdgcn_mfma_f32_16x16x32_f16(af[kk][fm], bf[fn], acc[fm][fn], 0, 0, 0);
  }

  // epilogue (+ optional fused column stats)
  float ss[4], ss2[4];
#pragma unroll
  for (int fn = 0; fn < 4; ++fn) { ss[fn] = 0.f; ss2[fn] = 0.f; }
#pragma unroll
  for (int fn = 0; fn < 4; ++fn) {
    int col = c0 + wc * 64 + fn * 16 + lrow;
    float bb = HAS_BIAS ? bias[col] : 0.f;
    if (HAS_BIAS && bias2 != nullptr) bb += bias2[col];
#pragma unroll
    for (int fm = 0; fm < 2; ++fm) {
      int grb = m0 + wr * 32 + fm * 16 + (lane >> 4) * 4;
#pragma unroll
      for (int j = 0; j < 4; ++j) {
        int gr = grb + j;
        if (gr < M) {
          float v = acc[fm][fn][j] + bb;
          if (HAS_ROWBIAS)
            v += rowbias[batch[gr] * ldc + col];
          if (STATS) { ss[fn] += v; ss2[fn] += v * v; }
          if (OUT_F16)
            Ch[(long long)gr * ldc + col] = __float2half(v);
          else
            Cf[(long long)gr * ldc + col] = v;
        }
      }
    }
  }
  if (STATS) {
    __shared__ float sred[2][4][4][16];   // [s|s2][wid][fn][lrow]
#pragma unroll
    for (int fn = 0; fn < 4; ++fn) {
      float s = ss[fn], s2 = ss2[fn];
      s += __shfl_xor(s, 16);  s += __shfl_xor(s, 32);
      s2 += __shfl_xor(s2, 16); s2 += __shfl_xor(s2, 32);
      if (lane < 16) { sred[0][wid][fn][lane] = s; sred[1][wid][fn][lane] = s2; }
    }
    __syncthreads();
    if (wr == 0 && lane < 16) {           // waves 0,1 combine with waves 2,3
#pragma unroll
      for (int fn = 0; fn < 4; ++fn) {
        int col = c0 + wc * 64 + fn * 16 + lane;
        atomicAdd(&stats[col],       sred[0][wid][fn][lane] + sred[0][wid + 2][fn][lane]);
        atomicAdd(&stats[ldc + col], sred[1][wid][fn][lane] + sred[1][wid + 2][fn][lane]);
      }
    }
  }
}

// ---------------------------------------------------------------------------
// Generic fp32 vector GEMM for the small (G-row) matmuls.
// STATS: fused column sum/sumsq into stats[0:128], stats[ldw:ldw+128] via LDS.
template<int K, bool HAS_BIAS, bool HAS_ROWBIAS, bool RELU, bool STATS>
__global__ __launch_bounds__(256) void k_gemm(
    const float* __restrict__ A1,
    const float* __restrict__ W, int ldw,
    const float* __restrict__ bias,
    const float* __restrict__ rowbias, const int* __restrict__ batch,
    float* __restrict__ C, float* __restrict__ stats, int M) {
  __shared__ float As[32 * K];
  constexpr int K4 = K / 4;
  int tid = threadIdx.x;
  int m0 = blockIdx.x * 32;
#pragma unroll
  for (int it = 0; it < K / 32; ++it) {
    int e4 = it * 256 + tid;
    int r = e4 / K4;
    int k4 = e4 % K4;
    int gr = m0 + r;
    float4 v = make_float4(0.f, 0.f, 0.f, 0.f);
    if (gr < M) v = reinterpret_cast<const float4*>(A1)[(long long)gr * K4 + k4];
    reinterpret_cast<float4*>(As)[e4] = v;
  }
  __shared__ float cs[128], cs2[128];
  if (STATS && tid < 128) { cs[tid] = 0.f; cs2[tid] = 0.f; }
  __syncthreads();

  int cg = tid & 31;
  int rg = tid >> 5;
  int col = blockIdx.y * 128 + cg * 4;
  float4 acc[4];
#pragma unroll
  for (int j = 0; j < 4; ++j) acc[j] = make_float4(0.f, 0.f, 0.f, 0.f);
  const float4* W4 = reinterpret_cast<const float4*>(W);
  const float4* As4 = reinterpret_cast<const float4*>(As);
#pragma unroll 8
  for (int k = 0; k < K; k += 4) {
    float4 w0 = W4[((k + 0) * ldw + col) >> 2];
    float4 w1 = W4[((k + 1) * ldw + col) >> 2];
    float4 w2 = W4[((k + 2) * ldw + col) >> 2];
    float4 w3 = W4[((k + 3) * ldw + col) >> 2];
#pragma unroll
    for (int j = 0; j < 4; ++j) {
      float4 a = As4[(rg + j * 8) * K4 + (k >> 2)];
      acc[j].x += a.x * w0.x + a.y * w1.x + a.z * w2.x + a.w * w3.x;
      acc[j].y += a.x * w0.y + a.y * w1.y + a.z * w2.y + a.w * w3.y;
      acc[j].z += a.x * w0.z + a.y * w1.z + a.z * w2.z + a.w * w3.z;
      acc[j].w += a.x * w0.w + a.y * w1.w + a.z * w2.w + a.w * w3.w;
    }
  }
  float4 bb = make_float4(0.f, 0.f, 0.f, 0.f);
  if (HAS_BIAS) bb = reinterpret_cast<const float4*>(bias)[blockIdx.y * 32 + cg];
  float ps[4] = {0.f, 0.f, 0.f, 0.f}, ps2[4] = {0.f, 0.f, 0.f, 0.f};
#pragma unroll
  for (int j = 0; j < 4; ++j) {
    int gr = m0 + rg + j * 8;
    if (gr < M) {
      float4 v = acc[j];
      v.x += bb.x; v.y += bb.y; v.z += bb.z; v.w += bb.w;
      if (HAS_ROWBIAS) {
        int b = batch[gr];
        float4 rb = reinterpret_cast<const float4*>(rowbias)[((long long)b * ldw + col) >> 2];
        v.x += rb.x; v.y += rb.y; v.z += rb.z; v.w += rb.w;
      }
      if (RELU) {
        v.x = fmaxf(v.x, 0.f); v.y = fmaxf(v.y, 0.f);
        v.z = fmaxf(v.z, 0.f); v.w = fmaxf(v.w, 0.f);
      }
      if (STATS) {
        ps[0] += v.x; ps2[0] += v.x * v.x;
        ps[1] += v.y; ps2[1] += v.y * v.y;
        ps[2] += v.z; ps2[2] += v.z * v.z;
        ps[3] += v.w; ps2[3] += v.w * v.w;
      }
      reinterpret_cast<float4*>(C)[((long long)gr * ldw + col) >> 2] = v;
    }
  }
  if (STATS) {
#pragma unroll
    for (int jc = 0; jc < 4; ++jc) {
      atomicAdd(&cs[cg * 4 + jc], ps[jc]);
      atomicAdd(&cs2[cg * 4 + jc], ps2[jc]);
    }
    __syncthreads();
    if (tid < 128) {
      atomicAdd(&stats[blockIdx.y * 128 + tid], cs[tid]);
      atomicAdd(&stats[ldw + blockIdx.y * 128 + tid], cs2[tid]);
    }
  }
}

// ---------------------------------------------------------------------------
// h16 = (half) relu(bn(z16)); half2 lanes, grid = N*64/256 = 12500 exact
__global__ void k_bn16(const __half* __restrict__ X16, const float* __restrict__ stats,
                       const float* __restrict__ gam, const float* __restrict__ beta,
                       __half* __restrict__ out16, float invM) {
  int i2 = blockIdx.x * 256 + threadIdx.x;
  int c = (i2 & 63) * 2;
  __half2 xv = reinterpret_cast<const __half2*>(X16)[i2];
  float m0 = stats[c] * invM;
  float v0 = stats[128 + c] * invM - m0 * m0;
  float m1 = stats[c + 1] * invM;
  float v1 = stats[128 + c + 1] * invM - m1 * m1;
  float r0 = fmaxf((__low2float(xv) - m0) * rsqrtf(v0 + EPS) * gam[c] + beta[c], 0.f);
  float r1 = fmaxf((__high2float(xv) - m1) * rsqrtf(v1 + EPS) * gam[c + 1] + beta[c + 1], 0.f);
  reinterpret_cast<__half2*>(out16)[i2] = __floats2half2_rn(r0, r1);
}

// pooled[g][c] = sum over graph-g rows of relu(bn(z2_16[r][c])).
// Per-graph blocks via gstart; 4-way row-parallel (512 threads) + LDS reduce.
__global__ void k_pool(const __half* __restrict__ z2_16, const float* __restrict__ stats,
                       const float* __restrict__ gam, const float* __restrict__ beta,
                       const int* __restrict__ gstart, float* __restrict__ pooled) {
  int tid = threadIdx.x;            // 512
  int rsub = tid >> 7;              // 0..3
  int cl = tid & 127;
  int g = blockIdx.x;
  int c = blockIdx.y * 128 + cl;    // grid (G,2)
  const float invM = 1.f / (float)N;
  float mean = stats[c] * invM;
  float var = stats[256 + c] * invM - mean * mean;
  float scale = rsqrtf(var + EPS) * gam[c];
  float shift = beta[c] - mean * scale;
  int r0 = gstart[g], r1 = gstart[g + 1];
  float acc = 0.f;
  for (int r = r0 + rsub; r < r1; r += 4) {
    float v = __half2float(z2_16[(long long)r * 256 + c]);
    acc += fmaxf(v * scale + shift, 0.f);
  }
  __shared__ float sred[512];
  sred[tid] = acc;
  __syncthreads();
  if (rsub == 0)
    pooled[g * 256 + c] = sred[cl] + sred[128 + cl] + sred[256 + cl] + sred[384 + cl];
}

// vn = relu(bn(zvn)); also write into hg concat buffer at layer offset
__global__ void k_vnapply(const float* __restrict__ zvn, const float* __restrict__ stats,
                          const float* __restrict__ gam, const float* __restrict__ beta,
                          float* __restrict__ vn, float* __restrict__ hgbuf, int layer) {
  int idx = blockIdx.x * 256 + threadIdx.x;  // G*H = 65536
  int c = idx & 127;
  int g = idx >> 7;
  const float invM = 1.f / (float)G;
  float mean = stats[c] * invM;
  float var = stats[128 + c] * invM - mean * mean;
  float v = fmaxf((zvn[idx] - mean) * rsqrtf(var + EPS) * gam[c] + beta[c], 0.f);
  vn[idx] = v;
  hgbuf[g * 384 + layer * 128 + c] = v;
}

// out[g] = hg2[g] @ pred_W2 + b2   (one wave per graph)
__global__ void k_pred2(const float* __restrict__ hg2, const float* __restrict__ W2,
                        const float* __restrict__ b2, float* __restrict__ out) {
  int g = blockIdx.x;
  int lane = threadIdx.x;
  float s = 0.f;
  for (int k = lane; k < 384; k += 64) s += hg2[g * 384 + k] * W2[k];
  for (int off = 32; off; off >>= 1) s += __shfl_down(s, off);
  if (lane == 0) out[g] = s + b2[0];
}

// ---------------------------------------------------------------------------
extern "C" void kernel_launch(void* const* d_in, const int* in_sizes, int n_in,
                              void* d_out, int out_size, void* d_ws, size_t ws_size,
                              hipStream_t stream) {
  const float* x         = (const float*)d_in[0];
  const float* edge_attr = (const float*)d_in[1];
  const float* atom_W    = (const float*)d_in[2];
  const float* atom_b    = (const float*)d_in[3];
  const float* vn_emb    = (const float*)d_in[4];
  const float* conv_We   = (const float*)d_in[5];
  const float* conv_be   = (const float*)d_in[6];
  const float* conv_W    = (const float*)d_in[7];
  const float* conv_b    = (const float*)d_in[8];
  const float* conv_g    = (const float*)d_in[9];
  const float* conv_beta = (const float*)d_in[10];
  const float* vn1_W     = (const float*)d_in[11];
  const float* vn1_b     = (const float*)d_in[12];
  const float* vn1_g     = (const float*)d_in[13];
  const float* vn1_beta  = (const float*)d_in[14];
  const float* vn2_W     = (const float*)d_in[15];
  const float* vn2_b     = (const float*)d_in[16];
  const float* vn2_g     = (const float*)d_in[17];
  const float* vn2_beta  = (const float*)d_in[18];
  const float* pred_W1   = (const float*)d_in[19];
  const float* pred_b1   = (const float*)d_in[20];
  const float* pred_W2   = (const float*)d_in[21];
  const float* pred_b2   = (const float*)d_in[22];
  const int*   eidx      = (const int*)d_in[23];
  const int*   batch     = (const int*)d_in[24];
  const int* src = eidx;
  const int* dst = eidx + E;

  // Workspace layout (units: 4-byte slots). Total ~24.1M slots = ~96.5 MB.
  float* ws    = (float*)d_ws;
  __half* h16  = (__half*)ws;                  // N*128 halves
  float* bufB  = ws + NH / 2;                  // 2*NH slots
  __half* hpa16= (__half*)bufB;                // N*128 halves  [B 0 .. NH/2)
  __half* z16  = (__half*)(bufB + NH / 2);     // N*128 halves  [B NH/2 .. NH)
  __half* x16  = z16;                          // alias (dead before conv gemm)
  __half* z2_16= (__half*)(bufB + NH);         // N*256 halves  [B NH .. 2NH)
  float* smallz= bufB + 2 * NH;
  float* U     = smallz;                       // G*256
  float* pooled= U + G * 256;                  // G*256
  float* zvn   = pooled + G * 256;             // G*128
  float* vn    = zvn + G * 128;                // G*128
  float* hgbuf = vn + G * 128;                 // G*384
  float* hg2   = hgbuf + G * 384;              // G*384
  float* statsz= hg2 + G * 384;                // 3*1024 (per-layer slices)
  int*   gstart= (int*)(statsz + 3 * 1024);    // G+1 (pad 516)
  __half* atomWt = (__half*)(gstart + 516);    // 128*128 halves
  __half* convWt = atomWt + 16384;             // 3 * 128*128
  __half* z2Wt   = convWt + 3 * 16384;         // 3 * 256*128
  int*  off    = (int*)(z2Wt + 3 * 32768);     // N+1 (padded 50002)
  int*  srcp   = off + 50002;                  // E ints (dst-sorted src*64)
  __half* eap  = (__half*)(srcp + E);          // E*16 halves (dst-sorted fp16 ea)
  // CSR build temporaries (dead before first k_agg) alias bufB:
  int* cnt  = (int*)bufB;                      // N
  int* cur  = cnt + N;                         // N
  int* bsum = cur + N;                         // NB_SCAN
  int* eidp = cur + N + 256;                   // E (dst-sorted edge ids)

  dim3 b256(256);

  // ---- CSR build (once; edge_index identical across layers) ----
  hipMemsetAsync(cnt, 0, (size_t)(2 * N + NB_SCAN) * 4, stream);  // cnt+cur+bsum
  hipMemsetAsync(statsz, 0, 3 * 1024 * 4, stream);
  k_hist<<<E / 256, b256, 0, stream>>>(dst, cnt);
  k_scan_block<<<NB_SCAN, b256, 0, stream>>>(cnt, off, bsum);
  k_scan_bsum<<<1, b256, 0, stream>>>(bsum);
  k_scan_add<<<NB_SCAN, b256, 0, stream>>>(off, bsum);
  k_scatter_idx<<<E / 256, b256, 0, stream>>>(dst, off, cur, eidp);
  k_permute<<<E / 256, b256, 0, stream>>>(eidp, src, edge_attr, srcp, eap);
  k_gstart<<<1, G, 0, stream>>>(batch, gstart);

  k_init_vn<<<G * 128 / 256, b256, 0, stream>>>(vn_emb, vn);

  // ---- weight/input fp16 prep ----
  k_tof16<<<(N * 128 / 4 + 255) / 256, b256, 0, stream>>>(x, x16, N * 128 / 4);
  k_wt<<<dim3(64, 1), b256, 0, stream>>>(atom_W, atomWt, 128, 0, 128, 0, 0);
  k_wt<<<dim3(64, 3), b256, 0, stream>>>(conv_W, convWt, 128, 0, 128, 16384, 16384);
  k_wt<<<dim3(128, 3), b256, 0, stream>>>(vn1_W, z2Wt, 256, 128, 256, 65536, 32768);

  // h16 = x16 @ atom_W + (atom_b + vn_emb)   (layer-0 addvn folded)
  k_mgemm<true, false, true, false><<<dim3(782, 1), b256, 0, stream>>>(
      x16, atomWt, atom_b, vn_emb, nullptr, nullptr, nullptr, h16, nullptr, 128, N);

  for (int i = 0; i < 3; ++i) {
    float* SZ = statsz + i * 1024;   // conv: +0 (256), z2: +256 (512), zvn: +768 (256)
    if (i > 0) k_addvn16<<<12500, b256, 0, stream>>>(h16, vn, batch);
    // hpa16 = h16 + sum_in relu(h16[src] + ea@We + be)  (2 half-grid dispatches)
    k_agg<<<6250, b256, 0, stream>>>(eap, conv_We + i * 2048, conv_be + i * 128,
                                     off, srcp, h16, hpa16, 0);
    k_agg<<<6250, b256, 0, stream>>>(eap, conv_We + i * 2048, conv_be + i * 128,
                                     off, srcp, h16, hpa16, 25000);
    // z16 = hpa16 @ conv_W[i] + conv_b[i]   (MFMA, fp16 out, fused stats)
    k_mgemm<true, false, true, true><<<dim3(782, 1), b256, 0, stream>>>(
        hpa16, convWt + i * 16384, conv_b + i * 128, nullptr, nullptr, nullptr,
        nullptr, z16, SZ, 128, N);
    // h16 = relu(bn(z16))
    k_bn16<<<12500, b256, 0, stream>>>(z16, SZ, conv_g + i * 128, conv_beta + i * 128,
                                       h16, 1.f / (float)N);
    // U = vn @ vn1_W[i][:128,:] + vn1_b[i]   (512 distinct rows of vn[batch])
    k_gemm<128, true, false, false, false><<<dim3(16, 2), b256, 0, stream>>>(
        vn, vn1_W + i * 256 * 256, 256, vn1_b + i * 256, nullptr, nullptr, U, nullptr, G);
    // z2_16 = h16 @ vn1_W[i][128:,:] + U[batch]   (MFMA, fp16 out, fused stats)
    k_mgemm<false, true, true, true><<<dim3(782, 2), b256, 0, stream>>>(
        h16, z2Wt + i * 32768, nullptr, nullptr, U, batch, nullptr, z2_16,
        SZ + 256, 256, N);
    // pooled[g] = sum relu(bn(z2_16))   (per-graph, 4-way row-parallel)
    k_pool<<<dim3(G, 2), dim3(512), 0, stream>>>(
        z2_16, SZ + 256, vn1_g + i * 256, vn1_beta + i * 256, gstart, pooled);
    // zvn = pooled @ vn2_W[i] + vn2_b[i]  (fused stats)
    k_gemm<256, true, false, false, true><<<dim3(16, 1), b256, 0, stream>>>(
        pooled, vn2_W + i * 256 * 128, 128, vn2_b + i * 128, nullptr, nullptr,
        zvn, SZ + 768, G);
    k_vnapply<<<G * 128 / 256, b256, 0, stream>>>(
        zvn, SZ + 768, vn2_g + i * 128, vn2_beta + i * 128, vn, hgbuf, i);
  }
  // hg2 = relu(hgbuf @ pred_W1 + pred_b1)
  k_gemm<384, true, false, true, false><<<dim3(16, 3), b256, 0, stream>>>(
      hgbuf, pred_W1, 384, pred_b1, nullptr, nullptr, hg2, nullptr, G);
  k_pred2<<<G, 64, 0, stream>>>(hg2, pred_W2, pred_b2, (float*)d_out);
}

// Round 11
// 1098.422 us; speedup vs baseline: 1.2643x; 1.1017x over previous
//
#include <hip/hip_runtime.h>
#include <hip/hip_fp16.h>

// Problem constants (fixed by the reference)
constexpr int N = 50000;
constexpr int E = 800000;
constexpr int G = 512;
constexpr int H = 128;
constexpr long long NH = (long long)N * H;   // 6,400,000 elements
constexpr float EPS = 1e-5f;
constexpr int NB_SCAN = 196;                 // ceil(50000/256)

typedef _Float16 f16x8 __attribute__((ext_vector_type(8)));
typedef _Float16 f16x2 __attribute__((ext_vector_type(2)));
typedef float f32x4 __attribute__((ext_vector_type(4)));

// ---------------------------------------------------------------------------
// vn[g][c] = vn_emb[c]
__global__ void k_init_vn(const float* __restrict__ vn_emb, float* __restrict__ vn) {
  int idx = blockIdx.x * 256 + threadIdx.x;   // G*H = 65536 exactly
  vn[idx] = vn_emb[idx & 127];
}

// fp32 -> fp16 bulk convert (float4 -> half2 x2), grid covers n4 exactly
__global__ void k_tof16(const float* __restrict__ in, __half* __restrict__ out, int n4) {
  int i = blockIdx.x * 256 + threadIdx.x;
  if (i >= n4) return;
  float4 v = reinterpret_cast<const float4*>(in)[i];
  __half2* o = reinterpret_cast<__half2*>(out);
  o[i * 2]     = __floats2half2_rn(v.x, v.y);
  o[i * 2 + 1] = __floats2half2_rn(v.z, v.w);
}

// Wt[c][k] = (half) W[(row0+k)*ldw + c], K=128 fixed; one layer per blockIdx.y
__global__ void k_wt(const float* __restrict__ W, __half* __restrict__ Wt,
                     int ldw, int row0, int cols, long long wstride, int wtstride) {
  const float* Wl = W + (long long)blockIdx.y * wstride;
  __half* Wtl = Wt + (long long)blockIdx.y * wtstride;
  int idx = blockIdx.x * 256 + threadIdx.x;   // cols*128, exact multiple of 256
  int k = idx & 127, c = idx >> 7;
  Wtl[c * 128 + k] = __float2half(Wl[(long long)(row0 + k) * ldw + c]);
}

// h16[r][:] += vn[batch[r]][:]  (half2 lanes, grid = N*64/256 = 12500 exact)
__global__ void k_addvn16(__half* __restrict__ h16, const float* __restrict__ vn,
                          const int* __restrict__ batch) {
  int i2 = blockIdx.x * 256 + threadIdx.x;
  int r = i2 >> 6;
  int b = batch[r];
  __half2 hv = reinterpret_cast<__half2*>(h16)[i2];
  float2 vv = reinterpret_cast<const float2*>(vn)[(b << 6) + (i2 & 63)];
  reinterpret_cast<__half2*>(h16)[i2] =
      __floats2half2_rn(__low2float(hv) + vv.x, __high2float(hv) + vv.y);
}

// gstart[g] = lower_bound(batch, g); gstart[G] = N  (batch is sorted)
__global__ void k_gstart(const int* __restrict__ batch, int* __restrict__ gstart) {
  int g = threadIdx.x;   // one block of 512
  int lo = 0, hi = N;
  while (lo < hi) { int mid = (lo + hi) >> 1; if (batch[mid] < g) lo = mid + 1; else hi = mid; }
  gstart[g] = lo;
  if (g == 0) gstart[G] = N;
}

// ---------------------------------------------------------------------------
// CSR build: histogram -> 2-level exclusive scan -> idx-scatter -> gather-permute.
__global__ void k_hist(const int* __restrict__ dst, int* __restrict__ cnt) {
  int e = blockIdx.x * 256 + threadIdx.x;   // grid covers E exactly
  atomicAdd(&cnt[dst[e]], 1);
}

__global__ void k_scan_block(const int* __restrict__ cnt, int* __restrict__ off,
                             int* __restrict__ bsum) {
  __shared__ int s[256];
  int idx = blockIdx.x * 256 + threadIdx.x;
  int v = (idx < N) ? cnt[idx] : 0;
  s[threadIdx.x] = v;
  __syncthreads();
  for (int o = 1; o < 256; o <<= 1) {
    int t = (threadIdx.x >= o) ? s[threadIdx.x - o] : 0;
    __syncthreads();
    s[threadIdx.x] += t;
    __syncthreads();
  }
  if (idx < N) off[idx + 1] = s[threadIdx.x];
  if (threadIdx.x == 255) bsum[blockIdx.x] = s[255];
  if (idx == 0) off[0] = 0;
}

__global__ void k_scan_bsum(int* __restrict__ bsum) {   // single block
  __shared__ int s[256];
  int v = (threadIdx.x < NB_SCAN) ? bsum[threadIdx.x] : 0;
  s[threadIdx.x] = v;
  __syncthreads();
  for (int o = 1; o < 256; o <<= 1) {
    int t = (threadIdx.x >= o) ? s[threadIdx.x - o] : 0;
    __syncthreads();
    s[threadIdx.x] += t;
    __syncthreads();
  }
  if (threadIdx.x < NB_SCAN) bsum[threadIdx.x] = s[threadIdx.x];  // inclusive
}

__global__ void k_scan_add(int* __restrict__ off, const int* __restrict__ bsum) {
  int idx = blockIdx.x * 256 + threadIdx.x;
  if (idx < N && blockIdx.x > 0) off[idx + 1] += bsum[blockIdx.x - 1];
}

__global__ void k_scatter_idx(const int* __restrict__ dst, const int* __restrict__ off,
                              int* __restrict__ cur, int* __restrict__ eidp) {
  int e = blockIdx.x * 256 + threadIdx.x;   // grid covers E exactly
  int d = dst[e];
  int p = off[d] + atomicAdd(&cur[d], 1);
  eidp[p] = e;
}

__global__ void k_permute(const int* __restrict__ eidp, const int* __restrict__ src,
                          const float* __restrict__ edge_attr,
                          int* __restrict__ srcp, __half* __restrict__ eap) {
  int i = blockIdx.x * 256 + threadIdx.x;   // grid covers E exactly
  int e = eidp[i];
  srcp[i] = src[e] * 64;                    // pre-scaled half2 index
  const float4* ea4 = reinterpret_cast<const float4*>(edge_attr) + e * 4;
  float4 a0 = ea4[0], a1 = ea4[1], a2 = ea4[2], a3 = ea4[3];
  __half2 h01 = __floats2half2_rn(a0.x, a0.y);
  __half2 h23 = __floats2half2_rn(a0.z, a0.w);
  __half2 h45 = __floats2half2_rn(a1.x, a1.y);
  __half2 h67 = __floats2half2_rn(a1.z, a1.w);
  __half2 h89 = __floats2half2_rn(a2.x, a2.y);
  __half2 hab = __floats2half2_rn(a2.z, a2.w);
  __half2 hcd = __floats2half2_rn(a3.x, a3.y);
  __half2 hef = __floats2half2_rn(a3.z, a3.w);
  int4 lo = make_int4(__builtin_bit_cast(int, h01), __builtin_bit_cast(int, h23),
                      __builtin_bit_cast(int, h45), __builtin_bit_cast(int, h67));
  int4 hi = make_int4(__builtin_bit_cast(int, h89), __builtin_bit_cast(int, hab),
                      __builtin_bit_cast(int, hcd), __builtin_bit_cast(int, hef));
  int4* o = reinterpret_cast<int4*>(eap + (long long)i * 16);
  o[0] = lo;
  o[1] = hi;
}

// ---------------------------------------------------------------------------
// CSR aggregation, atomic-free, LDS-free, all-32-bit indexing. One 64-lane
// wave per dst node (2 adjacent cols/lane). We panel in registers (fdot2).
// 4 independent accumulator chains; NO cross-group double-buffer (round-9
// lesson: +24 VGPR halved occupancy and regressed — TLP does the hiding).
// hpa16[d] = h16[d] + sum_{e in in(d)} relu(h16[src[e]] + ea[e] @ We + be)
__global__ __launch_bounds__(256) void k_agg(
    const __half* __restrict__ eap, const float* __restrict__ We,
    const float* __restrict__ be, const int* __restrict__ off,
    const int* __restrict__ srcp, const __half* __restrict__ h16,
    __half* __restrict__ hpa16, int d0) {
  int tid = threadIdx.x;
  int lane = tid & 63;
  int c0 = lane * 2;
  f16x2 wc0[8], wc1[8];
#pragma unroll
  for (int kk = 0; kk < 8; ++kk) {
    f16x2 w0, w1;
    w0[0] = (_Float16)We[(2 * kk) * 128 + c0];
    w0[1] = (_Float16)We[(2 * kk + 1) * 128 + c0];
    w1[0] = (_Float16)We[(2 * kk) * 128 + c0 + 1];
    w1[1] = (_Float16)We[(2 * kk + 1) * 128 + c0 + 1];
    wc0[kk] = w0; wc1[kk] = w1;
  }
  float2 bev = reinterpret_cast<const float2*>(be)[lane];
  int d = d0 + blockIdx.x * 4 + (tid >> 6);
  int j0 = off[d], j1 = off[d + 1];
  const __half2* h2 = reinterpret_cast<const __half2*>(h16);
  const int4* e4 = reinterpret_cast<const int4*>(eap);
  float a0 = 0.f, a1 = 0.f, b0 = 0.f, b1 = 0.f;
  float p0 = 0.f, p1 = 0.f, q0 = 0.f, q1 = 0.f;
  int j = j0;
#define EDGE(J, A0, A1) do {                                                   \
    int s_ = srcp[(J)];                                                        \
    __half2 hv_ = h2[s_ + lane];                                               \
    int4 lo_ = e4[2 * (J)], hi_ = e4[2 * (J) + 1];                             \
    float ev0_ = bev.x, ev1_ = bev.y;                                          \
    ev0_ = __builtin_amdgcn_fdot2(__builtin_bit_cast(f16x2, lo_.x), wc0[0], ev0_, false); \
    ev1_ = __builtin_amdgcn_fdot2(__builtin_bit_cast(f16x2, lo_.x), wc1[0], ev1_, false); \
    ev0_ = __builtin_amdgcn_fdot2(__builtin_bit_cast(f16x2, lo_.y), wc0[1], ev0_, false); \
    ev1_ = __builtin_amdgcn_fdot2(__builtin_bit_cast(f16x2, lo_.y), wc1[1], ev1_, false); \
    ev0_ = __builtin_amdgcn_fdot2(__builtin_bit_cast(f16x2, lo_.z), wc0[2], ev0_, false); \
    ev1_ = __builtin_amdgcn_fdot2(__builtin_bit_cast(f16x2, lo_.z), wc1[2], ev1_, false); \
    ev0_ = __builtin_amdgcn_fdot2(__builtin_bit_cast(f16x2, lo_.w), wc0[3], ev0_, false); \
    ev1_ = __builtin_amdgcn_fdot2(__builtin_bit_cast(f16x2, lo_.w), wc1[3], ev1_, false); \
    ev0_ = __builtin_amdgcn_fdot2(__builtin_bit_cast(f16x2, hi_.x), wc0[4], ev0_, false); \
    ev1_ = __builtin_amdgcn_fdot2(__builtin_bit_cast(f16x2, hi_.x), wc1[4], ev1_, false); \
    ev0_ = __builtin_amdgcn_fdot2(__builtin_bit_cast(f16x2, hi_.y), wc0[5], ev0_, false); \
    ev1_ = __builtin_amdgcn_fdot2(__builtin_bit_cast(f16x2, hi_.y), wc1[5], ev1_, false); \
    ev0_ = __builtin_amdgcn_fdot2(__builtin_bit_cast(f16x2, hi_.z), wc0[6], ev0_, false); \
    ev1_ = __builtin_amdgcn_fdot2(__builtin_bit_cast(f16x2, hi_.z), wc1[6], ev1_, false); \
    ev0_ = __builtin_amdgcn_fdot2(__builtin_bit_cast(f16x2, hi_.w), wc0[7], ev0_, false); \
    ev1_ = __builtin_amdgcn_fdot2(__builtin_bit_cast(f16x2, hi_.w), wc1[7], ev1_, false); \
    A0 += fmaxf(__low2float(hv_) + ev0_, 0.f);                                 \
    A1 += fmaxf(__high2float(hv_) + ev1_, 0.f);                                \
  } while (0)
  for (; j + 3 < j1; j += 4) {
    EDGE(j, a0, a1);
    EDGE(j + 1, b0, b1);
    EDGE(j + 2, p0, p1);
    EDGE(j + 3, q0, q1);
  }
  for (; j < j1; ++j) EDGE(j, a0, a1);
#undef EDGE
  a0 += b0 + p0 + q0; a1 += b1 + p1 + q1;
  int di = d * 64 + lane;
  __half2 hd = h2[di];
  reinterpret_cast<__half2*>(hpa16)[di] =
      __floats2half2_rn(__low2float(hd) + a0, __high2float(hd) + a1);
}

// ---------------------------------------------------------------------------
// fp16 MFMA GEMM, K=128 fixed. C[M x ldc] fp32 (or fp16 when OUT_F16).
// A [M][128] f16 row-major; Bt [ldc][128] f16 with Bt[c][k] = W[k][c].
// Block: 64 rows x 128 cols, 4 waves in 2x2, wave tile 32x64.
// A is read DIRECTLY global->VGPR; only B goes through LDS (35 KB).
// STATS: fused column sum/sumsq -> atomicAdd into stats[0:ldc], stats[ldc:2ldc].
template<bool HAS_BIAS, bool HAS_ROWBIAS, bool OUT_F16, bool STATS>
__global__ __launch_bounds__(256) void k_mgemm(
    const __half* __restrict__ A, const __half* __restrict__ Bt,
    const float* __restrict__ bias, const float* __restrict__ bias2,
    const float* __restrict__ rowbias, const int* __restrict__ batch,
    float* __restrict__ Cf, __half* __restrict__ Ch,
    float* __restrict__ stats, int ldc, int M) {
  __shared__ _Float16 Bsh[128][136];   // +8 pad: row stride 272 B
  int tid = threadIdx.x;
  int m0 = blockIdx.x * 64;
  int c0 = blockIdx.y * 128;
  int wid = tid >> 6, lane = tid & 63;
  int wr = wid >> 1, wc = wid & 1;        // 2x2 wave grid, wave tile 32x64
  int lrow = lane & 15;
  int lk = (lane >> 4) * 8;

  // A fragments: direct global loads (issue before B staging for overlap)
  f16x8 af[4][2];
#pragma unroll
  for (int kk = 0; kk < 4; ++kk)
#pragma unroll
    for (int fm = 0; fm < 2; ++fm)
      af[kk][fm] = *reinterpret_cast<const f16x8*>(
          A + (m0 + wr * 32 + fm * 16 + lrow) * 128 + kk * 32 + lk);

  // stage B: 128 rows x 16 chunks = 2048 chunks
#pragma unroll
  for (int it = 0; it < 8; ++it) {
    int idx = it * 256 + tid;
    int r = idx >> 4, ck = idx & 15;
    f16x8 v = *reinterpret_cast<const f16x8*>(Bt + ((c0 + r) << 7) + ck * 8);
    *reinterpret_cast<f16x8*>(&Bsh[r][ck * 8]) = v;
  }
  __syncthreads();

  f32x4 acc[2][4];
#pragma unroll
  for (int fm = 0; fm < 2; ++fm)
#pragma unroll
    for (int fn = 0; fn < 4; ++fn) acc[fm][fn] = (f32x4){0.f, 0.f, 0.f, 0.f};

#pragma unroll
  for (int kk = 0; kk < 4; ++kk) {
    f16x8 bf[4];
#pragma unroll
    for (int fn = 0; fn < 4; ++fn)
      bf[fn] = *reinterpret_cast<const f16x8*>(&Bsh[wc * 64 + fn * 16 + lrow][kk * 32 + lk]);
#pragma unroll
    for (int fm = 0; fm < 2; ++fm)
#pragma unroll
      for (int fn = 0; fn < 4; ++fn)
        acc[fm][fn] = __builtin_amdgcn_mfma_f32_16x16x32_f16(af[kk][fm], bf[fn], acc[fm][fn], 0, 0, 0);
  }

  // epilogue (+ optional fused column stats)
  float ss[4], ss2[4];
#pragma unroll
  for (int fn = 0; fn < 4; ++fn) { ss[fn] = 0.f; ss2[fn] = 0.f; }
#pragma unroll
  for (int fn = 0; fn < 4; ++fn) {
    int col = c0 + wc * 64 + fn * 16 + lrow;
    float bb = HAS_BIAS ? bias[col] : 0.f;
    if (HAS_BIAS && bias2 != nullptr) bb += bias2[col];
#pragma unroll
    for (int fm = 0; fm < 2; ++fm) {
      int grb = m0 + wr * 32 + fm * 16 + (lane >> 4) * 4;
#pragma unroll
      for (int j = 0; j < 4; ++j) {
        int gr = grb + j;
        if (gr < M) {
          float v = acc[fm][fn][j] + bb;
          if (HAS_ROWBIAS)
            v += rowbias[batch[gr] * ldc + col];
          if (STATS) { ss[fn] += v; ss2[fn] += v * v; }
          if (OUT_F16)
            Ch[(long long)gr * ldc + col] = __float2half(v);
          else
            Cf[(long long)gr * ldc + col] = v;
        }
      }
    }
  }
  if (STATS) {
    __shared__ float sred[2][4][4][16];   // [s|s2][wid][fn][lrow]
#pragma unroll
    for (int fn = 0; fn < 4; ++fn) {
      float s = ss[fn], s2 = ss2[fn];
      s += __shfl_xor(s, 16);  s += __shfl_xor(s, 32);
      s2 += __shfl_xor(s2, 16); s2 += __shfl_xor(s2, 32);
      if (lane < 16) { sred[0][wid][fn][lane] = s; sred[1][wid][fn][lane] = s2; }
    }
    __syncthreads();
    if (wr == 0 && lane < 16) {           // waves 0,1 combine with waves 2,3
#pragma unroll
      for (int fn = 0; fn < 4; ++fn) {
        int col = c0 + wc * 64 + fn * 16 + lane;
        atomicAdd(&stats[col],       sred[0][wid][fn][lane] + sred[0][wid + 2][fn][lane]);
        atomicAdd(&stats[ldc + col], sred[1][wid][fn][lane] + sred[1][wid + 2][fn][lane]);
      }
    }
  }
}

// ---------------------------------------------------------------------------
// Split-K small GEMM for the latency-bound G-row matmuls. Grid
// (M/32, cols/128, K/KC). Each block computes a partial over K-chunk
// [kz*KC, (kz+1)*KC) and atomicAdd's fp32 into C (pre-zeroed); the kz==0
// block also adds bias. Post-ops (relu/stats) live in consumers. M % 32 == 0.
template<int KC, bool HAS_BIAS>
__global__ __launch_bounds__(256) void k_sgemm(
    const float* __restrict__ A1, int lda,
    const float* __restrict__ W, int ldw,
    const float* __restrict__ bias,
    float* __restrict__ C) {
  __shared__ float As[32 * KC];
  constexpr int K4 = KC / 4;
  int tid = threadIdx.x;
  int m0 = blockIdx.x * 32;
  int kbase = blockIdx.z * KC;
  for (int e4 = tid; e4 < 32 * K4; e4 += 256) {
    int r = e4 / K4, k4 = e4 % K4;
    reinterpret_cast<float4*>(As)[e4] = *reinterpret_cast<const float4*>(
        &A1[(long long)(m0 + r) * lda + kbase + k4 * 4]);
  }
  __syncthreads();

  int cg = tid & 31;
  int rg = tid >> 5;
  int col = blockIdx.y * 128 + cg * 4;
  float4 acc[4];
#pragma unroll
  for (int j = 0; j < 4; ++j) acc[j] = make_float4(0.f, 0.f, 0.f, 0.f);
  const float4* W4 = reinterpret_cast<const float4*>(W);
  const float4* As4 = reinterpret_cast<const float4*>(As);
#pragma unroll 4
  for (int k = 0; k < KC; k += 4) {
    float4 w0 = W4[((kbase + k + 0) * ldw + col) >> 2];
    float4 w1 = W4[((kbase + k + 1) * ldw + col) >> 2];
    float4 w2 = W4[((kbase + k + 2) * ldw + col) >> 2];
    float4 w3 = W4[((kbase + k + 3) * ldw + col) >> 2];
#pragma unroll
    for (int j = 0; j < 4; ++j) {
      float4 a = As4[(rg + j * 8) * K4 + (k >> 2)];
      acc[j].x += a.x * w0.x + a.y * w1.x + a.z * w2.x + a.w * w3.x;
      acc[j].y += a.x * w0.y + a.y * w1.y + a.z * w2.y + a.w * w3.y;
      acc[j].z += a.x * w0.z + a.y * w1.z + a.z * w2.z + a.w * w3.z;
      acc[j].w += a.x * w0.w + a.y * w1.w + a.z * w2.w + a.w * w3.w;
    }
  }
  float4 bb = make_float4(0.f, 0.f, 0.f, 0.f);
  if (HAS_BIAS && blockIdx.z == 0)
    bb = reinterpret_cast<const float4*>(bias)[blockIdx.y * 32 + cg];
#pragma unroll
  for (int j = 0; j < 4; ++j) {
    int gr = m0 + rg + j * 8;
    float* cp = &C[(long long)gr * ldw + col];
    atomicAdd(cp + 0, acc[j].x + bb.x);
    atomicAdd(cp + 1, acc[j].y + bb.y);
    atomicAdd(cp + 2, acc[j].z + bb.z);
    atomicAdd(cp + 3, acc[j].w + bb.w);
  }
}

// ---------------------------------------------------------------------------
// Column sum / sumsq over M rows of X[M][NC] -> stats[0:NC], stats[NC:2NC]
template<int NC>
__global__ void k_stats(const float* __restrict__ X, int M, float* __restrict__ stats) {
  constexpr int RP = 256 / NC;
  int c = threadIdx.x % NC;
  int rsub = threadIdx.x / NC;
  float s = 0.f, s2 = 0.f;
  for (int r = blockIdx.x * RP + rsub; r < M; r += gridDim.x * RP) {
    float v = X[(long long)r * NC + c];
    s += v; s2 += v * v;
  }
  if (RP > 1) {
    __shared__ float ls[512];
    ls[threadIdx.x] = s; ls[256 + threadIdx.x] = s2;
    __syncthreads();
    if (rsub == 0) {
#pragma unroll
      for (int j = 1; j < RP; ++j) { s += ls[j * NC + c]; s2 += ls[256 + j * NC + c]; }
    }
  }
  if (rsub == 0) { atomicAdd(&stats[c], s); atomicAdd(&stats[NC + c], s2); }
}

// ---------------------------------------------------------------------------
// h16 = (half) relu(bn(z16)); half2 lanes, grid = N*64/256 = 12500 exact
__global__ void k_bn16(const __half* __restrict__ X16, const float* __restrict__ stats,
                       const float* __restrict__ gam, const float* __restrict__ beta,
                       __half* __restrict__ out16, float invM) {
  int i2 = blockIdx.x * 256 + threadIdx.x;
  int c = (i2 & 63) * 2;
  __half2 xv = reinterpret_cast<const __half2*>(X16)[i2];
  float m0 = stats[c] * invM;
  float v0 = stats[128 + c] * invM - m0 * m0;
  float m1 = stats[c + 1] * invM;
  float v1 = stats[128 + c + 1] * invM - m1 * m1;
  float r0 = fmaxf((__low2float(xv) - m0) * rsqrtf(v0 + EPS) * gam[c] + beta[c], 0.f);
  float r1 = fmaxf((__high2float(xv) - m1) * rsqrtf(v1 + EPS) * gam[c + 1] + beta[c + 1], 0.f);
  reinterpret_cast<__half2*>(out16)[i2] = __floats2half2_rn(r0, r1);
}

// pooled[g][c] = sum over graph-g rows of relu(bn(z2_16[r][c])).
// Per-graph blocks via gstart; 4-way row-parallel (512 threads) + LDS reduce.
__global__ void k_pool(const __half* __restrict__ z2_16, const float* __restrict__ stats,
                       const float* __restrict__ gam, const float* __restrict__ beta,
                       const int* __restrict__ gstart, float* __restrict__ pooled) {
  int tid = threadIdx.x;            // 512
  int rsub = tid >> 7;              // 0..3
  int cl = tid & 127;
  int g = blockIdx.x;
  int c = blockIdx.y * 128 + cl;    // grid (G,2)
  const float invM = 1.f / (float)N;
  float mean = stats[c] * invM;
  float var = stats[256 + c] * invM - mean * mean;
  float scale = rsqrtf(var + EPS) * gam[c];
  float shift = beta[c] - mean * scale;
  int r0 = gstart[g], r1 = gstart[g + 1];
  float acc = 0.f;
  for (int r = r0 + rsub; r < r1; r += 4) {
    float v = __half2float(z2_16[(long long)r * 256 + c]);
    acc += fmaxf(v * scale + shift, 0.f);
  }
  __shared__ float sred[512];
  sred[tid] = acc;
  __syncthreads();
  if (rsub == 0)
    pooled[g * 256 + c] = sred[cl] + sred[128 + cl] + sred[256 + cl] + sred[384 + cl];
}

// vn = relu(bn(zvn)); also write into hg concat buffer at layer offset
__global__ void k_vnapply(const float* __restrict__ zvn, const float* __restrict__ stats,
                          const float* __restrict__ gam, const float* __restrict__ beta,
                          float* __restrict__ vn, float* __restrict__ hgbuf, int layer) {
  int idx = blockIdx.x * 256 + threadIdx.x;  // G*H = 65536
  int c = idx & 127;
  int g = idx >> 7;
  const float invM = 1.f / (float)G;
  float mean = stats[c] * invM;
  float var = stats[128 + c] * invM - mean * mean;
  float v = fmaxf((zvn[idx] - mean) * rsqrtf(var + EPS) * gam[c] + beta[c], 0.f);
  vn[idx] = v;
  hgbuf[g * 384 + layer * 128 + c] = v;
}

// out[g] = relu(hg2[g]) @ pred_W2 + b2   (one wave per graph; relu fused here
// because hg2 is now assembled by split-K atomics without a post-op pass)
__global__ void k_pred2(const float* __restrict__ hg2, const float* __restrict__ W2,
                        const float* __restrict__ b2, float* __restrict__ out) {
  int g = blockIdx.x;
  int lane = threadIdx.x;
  float s = 0.f;
  for (int k = lane; k < 384; k += 64) s += fmaxf(hg2[g * 384 + k], 0.f) * W2[k];
  for (int off = 32; off; off >>= 1) s += __shfl_down(s, off);
  if (lane == 0) out[g] = s + b2[0];
}

// ---------------------------------------------------------------------------
extern "C" void kernel_launch(void* const* d_in, const int* in_sizes, int n_in,
                              void* d_out, int out_size, void* d_ws, size_t ws_size,
                              hipStream_t stream) {
  const float* x         = (const float*)d_in[0];
  const float* edge_attr = (const float*)d_in[1];
  const float* atom_W    = (const float*)d_in[2];
  const float* atom_b    = (const float*)d_in[3];
  const float* vn_emb    = (const float*)d_in[4];
  const float* conv_We   = (const float*)d_in[5];
  const float* conv_be   = (const float*)d_in[6];
  const float* conv_W    = (const float*)d_in[7];
  const float* conv_b    = (const float*)d_in[8];
  const float* conv_g    = (const float*)d_in[9];
  const float* conv_beta = (const float*)d_in[10];
  const float* vn1_W     = (const float*)d_in[11];
  const float* vn1_b     = (const float*)d_in[12];
  const float* vn1_g     = (const float*)d_in[13];
  const float* vn1_beta  = (const float*)d_in[14];
  const float* vn2_W     = (const float*)d_in[15];
  const float* vn2_b     = (const float*)d_in[16];
  const float* vn2_g     = (const float*)d_in[17];
  const float* vn2_beta  = (const float*)d_in[18];
  const float* pred_W1   = (const float*)d_in[19];
  const float* pred_b1   = (const float*)d_in[20];
  const float* pred_W2   = (const float*)d_in[21];
  const float* pred_b2   = (const float*)d_in[22];
  const int*   eidx      = (const int*)d_in[23];
  const int*   batch     = (const int*)d_in[24];
  const int* src = eidx;
  const int* dst = eidx + E;

  // Workspace layout (units: 4-byte slots). Total ~24.1M slots = ~96.5 MB.
  float* ws    = (float*)d_ws;
  __half* h16  = (__half*)ws;                  // N*128 halves
  float* bufB  = ws + NH / 2;                  // 2*NH slots
  __half* hpa16= (__half*)bufB;                // N*128 halves  [B 0 .. NH/2)
  __half* z16  = (__half*)(bufB + NH / 2);     // N*128 halves  [B NH/2 .. NH)
  __half* x16  = z16;                          // alias (dead before conv gemm)
  __half* z2_16= (__half*)(bufB + NH);         // N*256 halves  [B NH .. 2NH)
  float* smallz= bufB + 2 * NH;
  float* U     = smallz;                       // G*256  (U and zvn contiguous ->
  float* zvn   = U + G * 256;                  // G*128   one memset covers both)
  float* pooled= zvn + G * 128;                // G*256
  float* vn    = pooled + G * 256;             // G*128
  float* hgbuf = vn + G * 128;                 // G*384
  float* hg2   = hgbuf + G * 384;              // G*384
  float* statsz= hg2 + G * 384;                // 3*1024 (per-layer slices)
  int*   gstart= (int*)(statsz + 3 * 1024);    // G+1 (pad 516)
  __half* atomWt = (__half*)(gstart + 516);    // 128*128 halves
  __half* convWt = atomWt + 16384;             // 3 * 128*128
  __half* z2Wt   = convWt + 3 * 16384;         // 3 * 256*128
  int*  off    = (int*)(z2Wt + 3 * 32768);     // N+1 (padded 50002)
  int*  srcp   = off + 50002;                  // E ints (dst-sorted src*64)
  __half* eap  = (__half*)(srcp + E);          // E*16 halves (dst-sorted fp16 ea)
  // CSR build temporaries (dead before first k_agg) alias bufB:
  int* cnt  = (int*)bufB;                      // N
  int* cur  = cnt + N;                         // N
  int* bsum = cur + N;                         // NB_SCAN
  int* eidp = cur + N + 256;                   // E (dst-sorted edge ids)

  dim3 b256(256);

  // ---- CSR build (once; edge_index identical across layers) ----
  hipMemsetAsync(cnt, 0, (size_t)(2 * N + NB_SCAN) * 4, stream);  // cnt+cur+bsum
  hipMemsetAsync(statsz, 0, 3 * 1024 * 4, stream);
  k_hist<<<E / 256, b256, 0, stream>>>(dst, cnt);
  k_scan_block<<<NB_SCAN, b256, 0, stream>>>(cnt, off, bsum);
  k_scan_bsum<<<1, b256, 0, stream>>>(bsum);
  k_scan_add<<<NB_SCAN, b256, 0, stream>>>(off, bsum);
  k_scatter_idx<<<E / 256, b256, 0, stream>>>(dst, off, cur, eidp);
  k_permute<<<E / 256, b256, 0, stream>>>(eidp, src, edge_attr, srcp, eap);
  k_gstart<<<1, G, 0, stream>>>(batch, gstart);

  k_init_vn<<<G * 128 / 256, b256, 0, stream>>>(vn_emb, vn);

  // ---- weight/input fp16 prep ----
  k_tof16<<<(N * 128 / 4 + 255) / 256, b256, 0, stream>>>(x, x16, N * 128 / 4);
  k_wt<<<dim3(64, 1), b256, 0, stream>>>(atom_W, atomWt, 128, 0, 128, 0, 0);
  k_wt<<<dim3(64, 3), b256, 0, stream>>>(conv_W, convWt, 128, 0, 128, 16384, 16384);
  k_wt<<<dim3(128, 3), b256, 0, stream>>>(vn1_W, z2Wt, 256, 128, 256, 65536, 32768);

  // h16 = x16 @ atom_W + (atom_b + vn_emb)   (layer-0 addvn folded)
  k_mgemm<true, false, true, false><<<dim3(782, 1), b256, 0, stream>>>(
      x16, atomWt, atom_b, vn_emb, nullptr, nullptr, nullptr, h16, nullptr, 128, N);

  for (int i = 0; i < 3; ++i) {
    float* SZ = statsz + i * 1024;   // conv: +0 (256), z2: +256 (512), zvn: +768 (256)
    hipMemsetAsync(U, 0, (size_t)G * (256 + 128) * 4, stream);  // U + zvn
    if (i > 0) k_addvn16<<<12500, b256, 0, stream>>>(h16, vn, batch);
    // hpa16 = h16 + sum_in relu(h16[src] + ea@We + be)  (2 half-grid dispatches)
    k_agg<<<6250, b256, 0, stream>>>(eap, conv_We + i * 2048, conv_be + i * 128,
                                     off, srcp, h16, hpa16, 0);
    k_agg<<<6250, b256, 0, stream>>>(eap, conv_We + i * 2048, conv_be + i * 128,
                                     off, srcp, h16, hpa16, 25000);
    // z16 = hpa16 @ conv_W[i] + conv_b[i]   (MFMA, fp16 out, fused stats)
    k_mgemm<true, false, true, true><<<dim3(782, 1), b256, 0, stream>>>(
        hpa16, convWt + i * 16384, conv_b + i * 128, nullptr, nullptr, nullptr,
        nullptr, z16, SZ, 128, N);
    // h16 = relu(bn(z16))
    k_bn16<<<12500, b256, 0, stream>>>(z16, SZ, conv_g + i * 128, conv_beta + i * 128,
                                       h16, 1.f / (float)N);
    // U = vn @ vn1_W[i][:128,:] + vn1_b[i]   (split-K: 128 blocks)
    k_sgemm<32, true><<<dim3(16, 2, 4), b256, 0, stream>>>(
        vn, 128, vn1_W + i * 256 * 256, 256, vn1_b + i * 256, U);
    // z2_16 = h16 @ vn1_W[i][128:,:] + U[batch]   (MFMA, fp16 out, fused stats)
    k_mgemm<false, true, true, true><<<dim3(782, 2), b256, 0, stream>>>(
        h16, z2Wt + i * 32768, nullptr, nullptr, U, batch, nullptr, z2_16,
        SZ + 256, 256, N);
    // pooled[g] = sum relu(bn(z2_16))   (per-graph, 4-way row-parallel)
    k_pool<<<dim3(G, 2), dim3(512), 0, stream>>>(
        z2_16, SZ + 256, vn1_g + i * 256, vn1_beta + i * 256, gstart, pooled);
    // zvn = pooled @ vn2_W[i] + vn2_b[i]   (split-K: 64 blocks) + stats pass
    k_sgemm<64, true><<<dim3(16, 1, 4), b256, 0, stream>>>(
        pooled, 256, vn2_W + i * 256 * 128, 128, vn2_b + i * 128, zvn);
    k_stats<128><<<16, b256, 0, stream>>>(zvn, G, SZ + 768);
    k_vnapply<<<G * 128 / 256, b256, 0, stream>>>(
        zvn, SZ + 768, vn2_g + i * 128, vn2_beta + i * 128, vn, hgbuf, i);
  }
  // hg2 = hgbuf @ pred_W1 + pred_b1   (split-K: 192 blocks; relu fused in pred2)
  hipMemsetAsync(hg2, 0, (size_t)G * 384 * 4, stream);
  k_sgemm<96, true><<<dim3(16, 3, 4), b256, 0, stream>>>(
      hgbuf, 384, pred_W1, 384, pred_b1, hg2);
  k_pred2<<<G, 64, 0, stream>>>(hg2, pred_W2, pred_b2, (float*)d_out);
}